// Round 12
// baseline (361.511 us; speedup 1.0000x reference)
//
#include <hip/hip_runtime.h>
#include <math.h>

#define D_MODEL 1024
#define D_INNER 2048
#define D_STATE 16
#define DT_RANK 64
#define SEQ 1024
#define BATCH 2
#define NLAYERS 2
#define ROWS (BATCH*SEQ)      // 2048
#define XDIM 96               // dt_rank + 2*d_state
#define XZLD (2*D_INNER)      // 4096

// chunked scan geometry (CL*NC == SEQ)
#define NC 16
#define CL 64
#define SDB 256

// GEMM2 split-K geometry
#define G2_ROWS 64
#define G2_KC 128
#define G2_BK 32
#define G2_KS (D_INNER / G2_KC)

typedef short bf16x8 __attribute__((ext_vector_type(8)));
typedef float f32x4  __attribute__((ext_vector_type(4)));

// ---------------- helpers ----------------
__device__ __forceinline__ unsigned short f2bf(float f) {
    union { float f; unsigned int u; } v; v.f = f;
    unsigned int u = v.u;
    return (unsigned short)((u + 0x7FFFu + ((u >> 16) & 1u)) >> 16);   // RNE
}
__device__ __forceinline__ float bf2f(unsigned short u) {
    union { unsigned int i; float f; } v; v.i = ((unsigned int)u) << 16; return v.f;
}

__device__ __forceinline__ void gload_lds16(const void* g, void* s) {
    __builtin_amdgcn_global_load_lds((const __attribute__((address_space(1))) void*)g,
                                     (__attribute__((address_space(3))) void*)s, 16, 0, 0);
}

// e1^(s+1) for s=0..15, depth-4 multiply tree
#define POW_TREE(E, e1)                                                         \
    E[0] = e1;          E[1] = e1 * e1;   E[2] = E[1] * e1;  E[3] = E[1] * E[1];\
    E[4] = E[3] * E[0]; E[5] = E[3] * E[1]; E[6] = E[3] * E[2]; E[7] = E[3] * E[3];\
    E[8] = E[7] * E[0]; E[9] = E[7] * E[1]; E[10] = E[7] * E[2]; E[11] = E[7] * E[3];\
    E[12] = E[7] * E[4]; E[13] = E[7] * E[5]; E[14] = E[7] * E[6]; E[15] = E[7] * E[7];

// ---------------- x = pe + condition (f32 out; paths B/C) ----------------
__global__ __launch_bounds__(256) void add_pe_kernel(const float* __restrict__ pe,
    const float* __restrict__ cond, float* __restrict__ X)
{
    int i = blockIdx.x * 256 + threadIdx.x;
    int total = ROWS * D_MODEL / 4;
    if (i >= total) return;
    int row  = i / (D_MODEL / 4);
    int l    = row & (SEQ - 1);
    int col4 = i - row * (D_MODEL / 4);
    float4 p = reinterpret_cast<const float4*>(pe)[l * (D_MODEL / 4) + col4];
    float4 c = reinterpret_cast<const float4*>(cond)[i];
    float4 r; r.x = p.x + c.x; r.y = p.y + c.y; r.z = p.z + c.z; r.w = p.w + c.w;
    reinterpret_cast<float4*>(X)[i] = r;
}

// ---------------- f32 -> bf16 conversions ----------------
__global__ __launch_bounds__(256) void conv_bf16_dense(const float* __restrict__ src,
    unsigned short* __restrict__ dst, int n4)
{
    int i = blockIdx.x * 256 + threadIdx.x;
    if (i >= n4) return;
    float4 v = reinterpret_cast<const float4*>(src)[i];
    ushort4 o; o.x = f2bf(v.x); o.y = f2bf(v.y); o.z = f2bf(v.z); o.w = f2bf(v.w);
    reinterpret_cast<ushort4*>(dst)[i] = o;
}

// one dispatch: all three weight tensors -> bf16 AND x = pe+cond -> bf16 (path A pre-loop)
#define WN1 (NLAYERS * 2 * D_INNER * D_MODEL / 4)
#define WN2 (NLAYERS * D_MODEL * D_INNER / 4)
#define WN3 (NLAYERS * D_INNER * DT_RANK / 4)
#define WN4 (ROWS * D_MODEL / 4)
__global__ __launch_bounds__(256) void conv_wall(const float* __restrict__ Win,
    const float* __restrict__ Wout, const float* __restrict__ Wdt,
    const float* __restrict__ pe, const float* __restrict__ cond,
    unsigned short* __restrict__ WINbf, unsigned short* __restrict__ WOUTbf,
    unsigned short* __restrict__ WDTbf, unsigned short* __restrict__ Xbf)
{
    int i = blockIdx.x * 256 + threadIdx.x;
    if (i < WN1) {
        float4 v = reinterpret_cast<const float4*>(Win)[i];
        ushort4 o; o.x = f2bf(v.x); o.y = f2bf(v.y); o.z = f2bf(v.z); o.w = f2bf(v.w);
        reinterpret_cast<ushort4*>(WINbf)[i] = o;
    } else if (i < WN1 + WN2) {
        int j = i - WN1;
        float4 v = reinterpret_cast<const float4*>(Wout)[j];
        ushort4 o; o.x = f2bf(v.x); o.y = f2bf(v.y); o.z = f2bf(v.z); o.w = f2bf(v.w);
        reinterpret_cast<ushort4*>(WOUTbf)[j] = o;
    } else if (i < WN1 + WN2 + WN3) {
        int j = i - WN1 - WN2;
        float4 v = reinterpret_cast<const float4*>(Wdt)[j];
        ushort4 o; o.x = f2bf(v.x); o.y = f2bf(v.y); o.z = f2bf(v.z); o.w = f2bf(v.w);
        reinterpret_cast<ushort4*>(WDTbf)[j] = o;
    } else if (i < WN1 + WN2 + WN3 + WN4) {
        int j = i - WN1 - WN2 - WN3;
        int row  = j / (D_MODEL / 4);
        int l    = row & (SEQ - 1);
        int col4 = j - row * (D_MODEL / 4);
        float4 p = reinterpret_cast<const float4*>(pe)[l * (D_MODEL / 4) + col4];
        float4 c = reinterpret_cast<const float4*>(cond)[j];
        ushort4 o;
        o.x = f2bf(p.x + c.x); o.y = f2bf(p.y + c.y);
        o.z = f2bf(p.z + c.z); o.w = f2bf(p.w + c.w);
        reinterpret_cast<ushort4*>(Xbf)[j] = o;
    }
}

__global__ __launch_bounds__(256) void conv_bf16_strided(const float* __restrict__ src,
    int ld, int cols, unsigned short* __restrict__ dst, int total4)
{
    int i = blockIdx.x * 256 + threadIdx.x;
    if (i >= total4) return;
    int c4  = cols / 4;
    int row = i / c4;
    int col = (i - row * c4) * 4;
    float4 v = *reinterpret_cast<const float4*>(src + (size_t)row * ld + col);
    ushort4 o; o.x = f2bf(v.x); o.y = f2bf(v.y); o.z = f2bf(v.z); o.w = f2bf(v.w);
    *reinterpret_cast<ushort4*>(dst + (size_t)row * cols + col) = o;
}

__global__ __launch_bounds__(256) void conv_bf16_dtcols(const float* __restrict__ XDBL,
    unsigned short* __restrict__ dst)
{
    int i = blockIdx.x * 256 + threadIdx.x;
    if (i >= ROWS * DT_RANK / 4) return;
    int m  = i >> 4;
    int c4 = (i & 15) * 4;
    float4 v = *reinterpret_cast<const float4*>(XDBL + (size_t)m * XDIM + c4);
    ushort4 o; o.x = f2bf(v.x); o.y = f2bf(v.y); o.z = f2bf(v.z); o.w = f2bf(v.w);
    *reinterpret_cast<ushort4*>(dst + (size_t)m * DT_RANK + c4) = o;
}

// ================= bf16 MFMA NT GEMM family =================
#define GBM 128
#define GBN 128
#define GBK 64

#define GEMM_STAGE(Ap, Bp, lda, ldb, koff)                                      \
    _Pragma("unroll")                                                           \
    for (int i_ = 0; i_ < 4; ++i_) {                                            \
        int off_ = w * 4096 + i_ * 1024 + l * 16;                               \
        int row_ = off_ >> 7;                                                   \
        int col_ = (off_ & 127) >> 1;                                           \
        gload_lds16(Ap + (size_t)(m0 + row_) * (lda) + (koff) + col_,           \
                    (char*)As + w * 4096 + i_ * 1024);                          \
    }                                                                           \
    _Pragma("unroll")                                                           \
    for (int i_ = 0; i_ < 4; ++i_) {                                            \
        int off_ = w * 4096 + i_ * 1024 + l * 16;                               \
        int row_ = off_ >> 7;                                                   \
        int col_ = (off_ & 127) >> 1;                                           \
        gload_lds16(Bp + (size_t)(n0 + row_) * (ldb) + (koff) + col_,           \
                    (char*)Bs + w * 4096 + i_ * 1024);                          \
    }

#define GEMM_MFMA_STEP                                                          \
    _Pragma("unroll")                                                           \
    for (int kk = 0; kk < 2; ++kk) {                                            \
        bf16x8 af[4], bfr[4];                                                   \
        _Pragma("unroll")                                                       \
        for (int m = 0; m < 4; ++m)                                             \
            af[m] = *(const bf16x8*)&As[(wr * 64 + m * 16 + fr) * GBK + kk * 32 + fq * 8]; \
        _Pragma("unroll")                                                       \
        for (int n = 0; n < 4; ++n)                                             \
            bfr[n] = *(const bf16x8*)&Bs[(wc * 64 + n * 16 + fr) * GBK + kk * 32 + fq * 8]; \
        _Pragma("unroll")                                                       \
        for (int m = 0; m < 4; ++m)                                             \
            _Pragma("unroll")                                                   \
            for (int n = 0; n < 4; ++n)                                         \
                acc[m][n] = __builtin_amdgcn_mfma_f32_16x16x32_bf16(af[m], bfr[n], acc[m][n], 0, 0, 0); \
    }

// f32 out, optional softplus epilogue (path B)
__global__ __launch_bounds__(256) void gemm_bf16_nt(const unsigned short* __restrict__ A,
    const unsigned short* __restrict__ B, float* __restrict__ C,
    int M, int N, int K, int ldc, const float* __restrict__ bias, int epilogue)
{
    __shared__ unsigned short As[GBM * GBK];
    __shared__ unsigned short Bs[GBN * GBK];
    int tid = threadIdx.x;
    int w = tid >> 6, l = tid & 63;
    int wr = w >> 1, wc = w & 1;
    int m0 = blockIdx.y * GBM, n0 = blockIdx.x * GBN;

    f32x4 acc[4][4];
    #pragma unroll
    for (int m = 0; m < 4; ++m)
        #pragma unroll
        for (int n = 0; n < 4; ++n) acc[m][n] = (f32x4){0.f, 0.f, 0.f, 0.f};
    int fr = l & 15, fq = l >> 4;

    for (int k0 = 0; k0 < K; k0 += GBK) {
        GEMM_STAGE(A, B, K, K, k0)
        __syncthreads();
        GEMM_MFMA_STEP
        __syncthreads();
    }

    #pragma unroll
    for (int m = 0; m < 4; ++m)
        #pragma unroll
        for (int n = 0; n < 4; ++n) {
            int col = n0 + wc * 64 + n * 16 + fr;
            #pragma unroll
            for (int j = 0; j < 4; ++j) {
                int row = m0 + wr * 64 + m * 16 + fq * 4 + j;
                float v = acc[m][n][j];
                if (epilogue == 1) {
                    v += bias[col];
                    v = fmaxf(v, 0.f) + log1pf(__expf(-fabsf(v)));
                }
                C[(size_t)row * ldc + col] = v;
            }
        }
}

// bf16 out, no epilogue (path A GEMM1)
__global__ __launch_bounds__(256) void gemm_bf16_nt_bfout(const unsigned short* __restrict__ A,
    const unsigned short* __restrict__ B, unsigned short* __restrict__ C,
    int M, int N, int K, int ldc)
{
    __shared__ unsigned short As[GBM * GBK];
    __shared__ unsigned short Bs[GBN * GBK];
    int tid = threadIdx.x;
    int w = tid >> 6, l = tid & 63;
    int wr = w >> 1, wc = w & 1;
    int m0 = blockIdx.y * GBM, n0 = blockIdx.x * GBN;

    f32x4 acc[4][4];
    #pragma unroll
    for (int m = 0; m < 4; ++m)
        #pragma unroll
        for (int n = 0; n < 4; ++n) acc[m][n] = (f32x4){0.f, 0.f, 0.f, 0.f};
    int fr = l & 15, fq = l >> 4;

    for (int k0 = 0; k0 < K; k0 += GBK) {
        GEMM_STAGE(A, B, K, K, k0)
        __syncthreads();
        GEMM_MFMA_STEP
        __syncthreads();
    }

    #pragma unroll
    for (int m = 0; m < 4; ++m)
        #pragma unroll
        for (int n = 0; n < 4; ++n) {
            int col = n0 + wc * 64 + n * 16 + fr;
            #pragma unroll
            for (int j = 0; j < 4; ++j) {
                int row = m0 + wr * 64 + m * 16 + fq * 4 + j;
                C[(size_t)row * ldc + col] = f2bf(acc[m][n][j]);
            }
        }
}

// softplus + bf16 out (GEMM3 path A)
__global__ __launch_bounds__(256) void gemm_bf16_sp_bfout(const unsigned short* __restrict__ A,
    const unsigned short* __restrict__ B, unsigned short* __restrict__ C,
    int M, int N, int K, int ldc, const float* __restrict__ bias)
{
    __shared__ unsigned short As[GBM * GBK];
    __shared__ unsigned short Bs[GBN * GBK];
    int tid = threadIdx.x;
    int w = tid >> 6, l = tid & 63;
    int wr = w >> 1, wc = w & 1;
    int m0 = blockIdx.y * GBM, n0 = blockIdx.x * GBN;

    f32x4 acc[4][4];
    #pragma unroll
    for (int m = 0; m < 4; ++m)
        #pragma unroll
        for (int n = 0; n < 4; ++n) acc[m][n] = (f32x4){0.f, 0.f, 0.f, 0.f};
    int fr = l & 15, fq = l >> 4;

    for (int k0 = 0; k0 < K; k0 += GBK) {
        GEMM_STAGE(A, B, K, K, k0)
        __syncthreads();
        GEMM_MFMA_STEP
        __syncthreads();
    }

    #pragma unroll
    for (int m = 0; m < 4; ++m)
        #pragma unroll
        for (int n = 0; n < 4; ++n) {
            int col = n0 + wc * 64 + n * 16 + fr;
            float bv = bias[col];
            #pragma unroll
            for (int j = 0; j < 4; ++j) {
                int row = m0 + wr * 64 + m * 16 + fq * 4 + j;
                float v = acc[m][n][j] + bv;
                v = fmaxf(v, 0.f) + log1pf(__expf(-fabsf(v)));   // stable softplus
                C[(size_t)row * ldc + col] = f2bf(v);
            }
        }
}

// ---------------- GEMM4 path A: 128x64 tile, no split-K, dual output ----------------
// grid (N/64, M/128). A:[M][lda] bf16, B:[N][ldb] bf16. Writes bf16 Cbf OR f32 Cf (dense ldc=N).
#define G4BN 64
__global__ __launch_bounds__(256) void gemm_bf16_nt64(const unsigned short* __restrict__ A, int lda,
    const unsigned short* __restrict__ B, int ldb,
    unsigned short* __restrict__ Cbf, float* __restrict__ Cf,
    int M, int N, int K)
{
    __shared__ unsigned short As[GBM * GBK];   // 16 KB
    __shared__ unsigned short Bs[G4BN * GBK];  // 8 KB
    int tid = threadIdx.x;
    int w = tid >> 6, l = tid & 63;
    int wr = w >> 1, wc = w & 1;               // 2x2 waves over 128x64
    int m0 = blockIdx.y * GBM, n0 = blockIdx.x * G4BN;

    f32x4 acc[4][2];
    #pragma unroll
    for (int m = 0; m < 4; ++m)
        #pragma unroll
        for (int n = 0; n < 2; ++n) acc[m][n] = (f32x4){0.f, 0.f, 0.f, 0.f};
    int fr = l & 15, fq = l >> 4;

    for (int k0 = 0; k0 < K; k0 += GBK) {
        // stage A (16 KB): wave w covers [w*4096, w*4096+4096)
        #pragma unroll
        for (int i_ = 0; i_ < 4; ++i_) {
            int off_ = w * 4096 + i_ * 1024 + l * 16;
            int row_ = off_ >> 7;
            int col_ = (off_ & 127) >> 1;
            gload_lds16(A + (size_t)(m0 + row_) * lda + k0 + col_,
                        (char*)As + w * 4096 + i_ * 1024);
        }
        // stage B (8 KB): wave w covers [w*2048, w*2048+2048), 2 iters
        #pragma unroll
        for (int i_ = 0; i_ < 2; ++i_) {
            int off_ = w * 2048 + i_ * 1024 + l * 16;
            int row_ = off_ >> 7;
            int col_ = (off_ & 127) >> 1;
            gload_lds16(B + (size_t)(n0 + row_) * ldb + k0 + col_,
                        (char*)Bs + w * 2048 + i_ * 1024);
        }
        __syncthreads();
        #pragma unroll
        for (int kk = 0; kk < 2; ++kk) {
            bf16x8 af[4], bfr[2];
            #pragma unroll
            for (int m = 0; m < 4; ++m)
                af[m] = *(const bf16x8*)&As[(wr * 64 + m * 16 + fr) * GBK + kk * 32 + fq * 8];
            #pragma unroll
            for (int n = 0; n < 2; ++n)
                bfr[n] = *(const bf16x8*)&Bs[(wc * 32 + n * 16 + fr) * GBK + kk * 32 + fq * 8];
            #pragma unroll
            for (int m = 0; m < 4; ++m)
                #pragma unroll
                for (int n = 0; n < 2; ++n)
                    acc[m][n] = __builtin_amdgcn_mfma_f32_16x16x32_bf16(af[m], bfr[n], acc[m][n], 0, 0, 0);
        }
        __syncthreads();
    }

    #pragma unroll
    for (int m = 0; m < 4; ++m)
        #pragma unroll
        for (int n = 0; n < 2; ++n) {
            int col = n0 + wc * 32 + n * 16 + fr;
            #pragma unroll
            for (int j = 0; j < 4; ++j) {
                int row = m0 + wr * 64 + m * 16 + fq * 4 + j;
                float v = acc[m][n][j];
                if (Cbf) Cbf[(size_t)row * N + col] = f2bf(v);
                else     Cf[(size_t)row * N + col] = v;
            }
        }
}

// ---------------- FUSED conv+silu + GEMM2 split-K (path A) ----------------
__global__ __launch_bounds__(256) void gemm2_fused(const unsigned short* __restrict__ XZbf,
    const float* __restrict__ cw, const float* __restrict__ cb,
    const float* __restrict__ B, unsigned short* __restrict__ XCbf,
    float* __restrict__ P)
{
    __shared__ float Axc[G2_KC][68];           // 34.8 KB
    __shared__ float Bs[G2_BK][XDIM + 1];      // 12.1 KB
    int tid = threadIdx.x;
    int m0 = blockIdx.x * G2_ROWS;
    int kc = blockIdx.y;
    int k0 = kc * G2_KC;

    // ---- phase 1: conv+silu ----
    {
        int d_loc = tid & 127;
        int d     = k0 + d_loc;
        int r0    = m0 + (tid >> 7) * 32;
        float4 wv = *(const float4*)(cw + (size_t)d * 4);
        float cbv = cb[d];
        int l0 = r0 & (SEQ - 1);
        float u3 = (l0 >= 3) ? bf2f(XZbf[(size_t)(r0 - 3) * XZLD + d]) : 0.f;
        float u2 = (l0 >= 2) ? bf2f(XZbf[(size_t)(r0 - 2) * XZLD + d]) : 0.f;
        float u1 = (l0 >= 1) ? bf2f(XZbf[(size_t)(r0 - 1) * XZLD + d]) : 0.f;
        int rl0 = r0 - m0;
        #pragma unroll 4
        for (int t = 0; t < 32; ++t) {
            float u0 = bf2f(XZbf[(size_t)(r0 + t) * XZLD + d]);
            float v = cbv + wv.x * u3 + wv.y * u2 + wv.z * u1 + wv.w * u0;
            v = v / (1.f + __expf(-v));        // silu
            Axc[d_loc][rl0 + t] = v;
            XCbf[(size_t)(r0 + t) * D_INNER + d] = f2bf(v);
            u3 = u2; u2 = u1; u1 = u0;
        }
    }
    __syncthreads();

    // ---- phase 2: GEMM ----
    int rg = tid >> 4;
    int cg = tid & 15;
    float acc[4][6];
    #pragma unroll
    for (int i = 0; i < 4; ++i)
        #pragma unroll
        for (int j = 0; j < 6; ++j) acc[i][j] = 0.f;

    for (int kb = 0; kb < G2_KC; kb += G2_BK) {
        {
            #pragma unroll
            for (int i = 0; i < 3; ++i) {
                int idx = tid + i * 256;
                int col = idx >> 3;
                int kk  = (idx & 7) * 4;
                float4 v = *(const float4*)(B + (size_t)col * D_INNER + k0 + kb + kk);
                Bs[kk + 0][col] = v.x;
                Bs[kk + 1][col] = v.y;
                Bs[kk + 2][col] = v.z;
                Bs[kk + 3][col] = v.w;
            }
        }
        __syncthreads();
        #pragma unroll
        for (int k = 0; k < G2_BK; ++k) {
            float4 a  = *(const float4*)&Axc[kb + k][rg * 4];
            float2 b0 = *(const float2*)&Bs[k][cg * 6];
            float2 b1 = *(const float2*)&Bs[k][cg * 6 + 2];
            float2 b2 = *(const float2*)&Bs[k][cg * 6 + 4];
            float av[4] = {a.x, a.y, a.z, a.w};
            float bv[6] = {b0.x, b0.y, b1.x, b1.y, b2.x, b2.y};
            #pragma unroll
            for (int i = 0; i < 4; ++i)
                #pragma unroll
                for (int j = 0; j < 6; ++j) acc[i][j] += av[i] * bv[j];
        }
        __syncthreads();
    }

    #pragma unroll
    for (int i = 0; i < 4; ++i)
        #pragma unroll
        for (int j = 0; j < 6; ++j)
            P[((size_t)kc * ROWS + m0 + rg * 4 + i) * XDIM + cg * 6 + j] = acc[i][j];
}

// ---------------- GEMM2 split-K (f32, path B) ----------------
__global__ __launch_bounds__(256) void gemm2_splitk(const float* __restrict__ A,
    const float* __restrict__ B, float* __restrict__ P)
{
    __shared__ float As[G2_BK][G2_ROWS];
    __shared__ float Bs[G2_BK][XDIM + 1];
    int tid = threadIdx.x;
    int m0 = blockIdx.x * G2_ROWS;
    int kc = blockIdx.y;
    int k0 = kc * G2_KC;

    int rg = tid >> 4;
    int cg = tid & 15;
    float acc[4][6];
    #pragma unroll
    for (int i = 0; i < 4; ++i)
        #pragma unroll
        for (int j = 0; j < 6; ++j) acc[i][j] = 0.f;

    for (int kb = 0; kb < G2_KC; kb += G2_BK) {
        {
            int row = tid & 63;
            int kk  = (tid >> 6) * 4;
            #pragma unroll
            for (int i = 0; i < 2; ++i) {
                float4 v = *(const float4*)(A + (size_t)(m0 + row) * D_INNER + k0 + kb + kk + i * 16);
                As[kk + i * 16 + 0][row] = v.x;
                As[kk + i * 16 + 1][row] = v.y;
                As[kk + i * 16 + 2][row] = v.z;
                As[kk + i * 16 + 3][row] = v.w;
            }
        }
        {
            #pragma unroll
            for (int i = 0; i < 3; ++i) {
                int idx = tid + i * 256;
                int col = idx >> 3;
                int kk  = (idx & 7) * 4;
                float4 v = *(const float4*)(B + (size_t)col * D_INNER + k0 + kb + kk);
                Bs[kk + 0][col] = v.x;
                Bs[kk + 1][col] = v.y;
                Bs[kk + 2][col] = v.z;
                Bs[kk + 3][col] = v.w;
            }
        }
        __syncthreads();
        #pragma unroll
        for (int k = 0; k < G2_BK; ++k) {
            float4 a  = *(const float4*)&As[k][rg * 4];
            float2 b0 = *(const float2*)&Bs[k][cg * 6];
            float2 b1 = *(const float2*)&Bs[k][cg * 6 + 2];
            float2 b2 = *(const float2*)&Bs[k][cg * 6 + 4];
            float av[4] = {a.x, a.y, a.z, a.w};
            float bv[6] = {b0.x, b0.y, b1.x, b1.y, b2.x, b2.y};
            #pragma unroll
            for (int i = 0; i < 4; ++i)
                #pragma unroll
                for (int j = 0; j < 6; ++j) acc[i][j] += av[i] * bv[j];
        }
        __syncthreads();
    }

    #pragma unroll
    for (int i = 0; i < 4; ++i)
        #pragma unroll
        for (int j = 0; j < 6; ++j)
            P[((size_t)kc * ROWS + m0 + rg * 4 + i) * XDIM + cg * 6 + j] = acc[i][j];
}

// reduce; optionally emit dt columns as bf16
__global__ __launch_bounds__(256) void gemm2_reduce(const float* __restrict__ P,
    float* __restrict__ XDBLo, unsigned short* __restrict__ dtbf)
{
    int i = blockIdx.x * 256 + threadIdx.x;
    if (i >= ROWS * XDIM / 4) return;
    float4 acc = make_float4(0.f, 0.f, 0.f, 0.f);
    #pragma unroll
    for (int ks = 0; ks < G2_KS; ++ks) {
        float4 v = *(const float4*)(P + (size_t)ks * ROWS * XDIM + (size_t)i * 4);
        acc.x += v.x; acc.y += v.y; acc.z += v.z; acc.w += v.w;
    }
    *(float4*)(XDBLo + (size_t)i * 4) = acc;
    if (dtbf) {
        int row = (i * 4) / XDIM;
        int col = (i * 4) - row * XDIM;
        if (col < DT_RANK) {
            ushort4 o; o.x = f2bf(acc.x); o.y = f2bf(acc.y); o.z = f2bf(acc.z); o.w = f2bf(acc.w);
            *reinterpret_cast<ushort4*>(dtbf + (size_t)row * DT_RANK + col) = o;
        }
    }
}

// ---------------- generic fp32 NT GEMM (fallback path C) ----------------
#define BM 64
#define BN 64
#define BK 16
__global__ __launch_bounds__(256) void gemm_nt(const float* __restrict__ A, int lda,
                                               const float* __restrict__ B, int ldb,
                                               float* __restrict__ C, int ldc,
                                               int M, int N, int K,
                                               const float* __restrict__ bias, int epilogue)
{
    __shared__ float As[BM][BK + 1];
    __shared__ float Bs[BN][BK + 1];
    int t  = threadIdx.x;
    int m0 = blockIdx.y * BM;
    int n0 = blockIdx.x * BN;
    int lrow = t >> 2;
    int lk   = (t & 3) * 4;
    int tm   = t >> 4;
    int tn   = t & 15;

    float acc[4][4];
    #pragma unroll
    for (int i = 0; i < 4; ++i)
        #pragma unroll
        for (int j = 0; j < 4; ++j) acc[i][j] = 0.f;

    for (int k0 = 0; k0 < K; k0 += BK) {
        {
            int row = m0 + lrow;
            float4 v = make_float4(0.f, 0.f, 0.f, 0.f);
            if (row < M) v = *reinterpret_cast<const float4*>(A + (size_t)row * lda + k0 + lk);
            As[lrow][lk + 0] = v.x; As[lrow][lk + 1] = v.y;
            As[lrow][lk + 2] = v.z; As[lrow][lk + 3] = v.w;
        }
        {
            int row = n0 + lrow;
            float4 v = make_float4(0.f, 0.f, 0.f, 0.f);
            if (row < N) v = *reinterpret_cast<const float4*>(B + (size_t)row * ldb + k0 + lk);
            Bs[lrow][lk + 0] = v.x; Bs[lrow][lk + 1] = v.y;
            Bs[lrow][lk + 2] = v.z; Bs[lrow][lk + 3] = v.w;
        }
        __syncthreads();
        #pragma unroll
        for (int kk = 0; kk < BK; ++kk) {
            float a[4], b[4];
            #pragma unroll
            for (int i = 0; i < 4; ++i) a[i] = As[tm * 4 + i][kk];
            #pragma unroll
            for (int j = 0; j < 4; ++j) b[j] = Bs[tn * 4 + j][kk];
            #pragma unroll
            for (int i = 0; i < 4; ++i)
                #pragma unroll
                for (int j = 0; j < 4; ++j) acc[i][j] += a[i] * b[j];
        }
        __syncthreads();
    }

    #pragma unroll
    for (int i = 0; i < 4; ++i) {
        int m = m0 + tm * 4 + i;
        if (m >= M) continue;
        #pragma unroll
        for (int j = 0; j < 4; ++j) {
            int n = n0 + tn * 4 + j;
            if (n >= N) continue;
            float v = acc[i][j];
            if (epilogue == 1) {
                v += bias[n];
                v = fmaxf(v, 0.f) + log1pf(__expf(-fabsf(v)));
            }
            C[(size_t)m * ldc + n] = v;
        }
    }
}

// ---------------- conv+silu, f32 (paths B/C) ----------------
__global__ __launch_bounds__(256) void conv_silu_kernel(const float* __restrict__ XZ,
    const float* __restrict__ cw, const float* __restrict__ cb, float* __restrict__ XC)
{
    int idx = blockIdx.x * 256 + threadIdx.x;
    if (idx >= ROWS * (D_INNER / 4)) return;
    int d4   = idx % (D_INNER / 4);
    int rl   = idx / (D_INNER / 4);
    int l    = rl & (SEQ - 1);
    int base = rl - l;
    int d    = d4 * 4;

    float4 acc = reinterpret_cast<const float4*>(cb)[d4];
    float w[4][4];
    #pragma unroll
    for (int dd = 0; dd < 4; ++dd) {
        float4 wv = *reinterpret_cast<const float4*>(cw + (size_t)(d + dd) * 4);
        w[dd][0] = wv.x; w[dd][1] = wv.y; w[dd][2] = wv.z; w[dd][3] = wv.w;
    }
    #pragma unroll
    for (int k = 0; k < 4; ++k) {
        int lr = l - 3 + k;
        if (lr < 0) continue;
        float4 u = *reinterpret_cast<const float4*>(XZ + (size_t)(base + lr) * XZLD + d);
        acc.x += w[0][k] * u.x; acc.y += w[1][k] * u.y;
        acc.z += w[2][k] * u.z; acc.w += w[3][k] * u.w;
    }
    acc.x = acc.x / (1.f + __expf(-acc.x));
    acc.y = acc.y / (1.f + __expf(-acc.y));
    acc.z = acc.z / (1.f + __expf(-acc.z));
    acc.w = acc.w / (1.f + __expf(-acc.w));
    reinterpret_cast<float4*>(XC)[idx] = acc;
}

// ================= chunked scan, thread-per-channel =================
// Fast path: when a[s] == -(s+1) (runtime-verified), exp(dl*a[s]) = exp(-dl)^(s+1).

// path A phase 1: delta bf16 dense (DL), u bf16 dense (XCbf)
__global__ __launch_bounds__(SDB) void scan_part1b(const unsigned short* __restrict__ XCbf,
    const unsigned short* __restrict__ DL, const float* __restrict__ XDBL,
    const float* __restrict__ A_log, float* __restrict__ Psum, float* __restrict__ Ssum)
{
    __shared__ float sB[CL][16];
    int tid = threadIdx.x;
    int d = blockIdx.x * SDB + tid;
    int c = blockIdx.y, b = blockIdx.z;
    size_t r0 = (size_t)b * SEQ + (size_t)c * CL;

    #pragma unroll
    for (int i = 0; i < (CL * 4) / SDB; ++i) {
        int idx = tid + i * SDB;
        int t = idx >> 2, j = (idx & 3) * 4;
        *(float4*)&sB[t][j] = *(const float4*)(XDBL + (r0 + t) * XDIM + DT_RANK + j);
    }

    float a[D_STATE], S[D_STATE];
    #pragma unroll
    for (int i = 0; i < 4; ++i) {
        float4 v = *(const float4*)(A_log + (size_t)d * D_STATE + i * 4);
        a[i*4+0] = -__expf(v.x); a[i*4+1] = -__expf(v.y);
        a[i*4+2] = -__expf(v.z); a[i*4+3] = -__expf(v.w);
    }
    bool powok = true;
    #pragma unroll
    for (int s = 0; s < D_STATE; ++s)
        powok = powok && (fabsf(a[s] + (float)(s + 1)) < 1e-3f * (float)(s + 1));
    #pragma unroll
    for (int s = 0; s < D_STATE; ++s) S[s] = 0.f;
    float sumdl = 0.f;
    __syncthreads();

    if (powok) {
        for (int t = 0; t < CL; ++t) {
            float dl = bf2f(DL[(r0 + t) * D_INNER + d]);
            float uu = bf2f(XCbf[(r0 + t) * D_INNER + d]);
            float du = dl * uu;
            sumdl += dl;
            float4 b0 = *(const float4*)&sB[t][0];
            float4 b1 = *(const float4*)&sB[t][4];
            float4 b2 = *(const float4*)&sB[t][8];
            float4 b3 = *(const float4*)&sB[t][12];
            float bv[16] = {b0.x,b0.y,b0.z,b0.w, b1.x,b1.y,b1.z,b1.w,
                            b2.x,b2.y,b2.z,b2.w, b3.x,b3.y,b3.z,b3.w};
            float e1 = __expf(-dl);
            float E[16];
            POW_TREE(E, e1)
            #pragma unroll
            for (int s = 0; s < D_STATE; ++s)
                S[s] = E[s] * S[s] + du * bv[s];
        }
    } else {
        for (int t = 0; t < CL; ++t) {
            float dl = bf2f(DL[(r0 + t) * D_INNER + d]);
            float uu = bf2f(XCbf[(r0 + t) * D_INNER + d]);
            float du = dl * uu;
            sumdl += dl;
            float4 b0 = *(const float4*)&sB[t][0];
            float4 b1 = *(const float4*)&sB[t][4];
            float4 b2 = *(const float4*)&sB[t][8];
            float4 b3 = *(const float4*)&sB[t][12];
            float bv[16] = {b0.x,b0.y,b0.z,b0.w, b1.x,b1.y,b1.z,b1.w,
                            b2.x,b2.y,b2.z,b2.w, b3.x,b3.y,b3.z,b3.w};
            #pragma unroll
            for (int s = 0; s < D_STATE; ++s) {
                float e = __expf(dl * a[s]);
                S[s] = e * S[s] + du * bv[s];
            }
        }
    }

    size_t o = (((size_t)b * NC + c) * D_INNER + d) * D_STATE;
    #pragma unroll
    for (int i = 0; i < 4; ++i) {
        float4 p, s4;
        p.x = __expf(a[i*4+0] * sumdl); p.y = __expf(a[i*4+1] * sumdl);
        p.z = __expf(a[i*4+2] * sumdl); p.w = __expf(a[i*4+3] * sumdl);
        s4.x = S[i*4+0]; s4.y = S[i*4+1]; s4.z = S[i*4+2]; s4.w = S[i*4+3];
        *(float4*)(Psum + o + i * 4) = p;
        *(float4*)(Ssum + o + i * 4) = s4;
    }
}

// chunk-level prefix, in place
__global__ __launch_bounds__(256) void scan_prefix(float* __restrict__ Psum,
    const float* __restrict__ Ssum)
{
    int idx = blockIdx.x * 256 + threadIdx.x;
    int b = idx >> 15;
    int rem = idx & 32767;
    float h = 0.f;
    for (int c = 0; c < NC; ++c) {
        size_t o = (((size_t)b * NC + c) * D_INNER * D_STATE) + rem;
        float p = Psum[o];
        float s = Ssum[o];
        Psum[o] = h;
        h = p * h + s;
    }
}

// path A phase 2: out bf16 in place (DL) -> GEMM4 A
__global__ __launch_bounds__(SDB) void scan_part2b(const unsigned short* __restrict__ XCbf,
    unsigned short* __restrict__ DL, const unsigned short* __restrict__ XZbf,
    const float* __restrict__ XDBL, const float* __restrict__ A_log,
    const float* __restrict__ Dp, const float* __restrict__ Hin)
{
    __shared__ float sBC[CL][32];
    int tid = threadIdx.x;
    int d = blockIdx.x * SDB + tid;
    int c = blockIdx.y, b = blockIdx.z;
    size_t r0 = (size_t)b * SEQ + (size_t)c * CL;

    #pragma unroll
    for (int i = 0; i < (CL * 8) / SDB; ++i) {
        int idx = tid + i * SDB;
        int t = idx >> 3, j = (idx & 7) * 4;
        *(float4*)&sBC[t][j] = *(const float4*)(XDBL + (r0 + t) * XDIM + DT_RANK + j);
    }

    float a[D_STATE], h[D_STATE];
    #pragma unroll
    for (int i = 0; i < 4; ++i) {
        float4 v = *(const float4*)(A_log + (size_t)d * D_STATE + i * 4);
        a[i*4+0] = -__expf(v.x); a[i*4+1] = -__expf(v.y);
        a[i*4+2] = -__expf(v.z); a[i*4+3] = -__expf(v.w);
    }
    bool powok = true;
    #pragma unroll
    for (int s = 0; s < D_STATE; ++s)
        powok = powok && (fabsf(a[s] + (float)(s + 1)) < 1e-3f * (float)(s + 1));
    size_t ho = (((size_t)b * NC + c) * D_INNER + d) * D_STATE;
    #pragma unroll
    for (int i = 0; i < 4; ++i) {
        float4 v = *(const float4*)(Hin + ho + i * 4);
        h[i*4+0] = v.x; h[i*4+1] = v.y; h[i*4+2] = v.z; h[i*4+3] = v.w;
    }
    float dp = Dp[d];
    __syncthreads();

    if (powok) {
        for (int t = 0; t < CL; ++t) {
            float dl = bf2f(DL[(r0 + t) * D_INNER + d]);
            float uu = bf2f(XCbf[(r0 + t) * D_INNER + d]);
            float z  = bf2f(XZbf[(r0 + t) * XZLD + D_INNER + d]);
            float du = dl * uu;
            float4 b0 = *(const float4*)&sBC[t][0];
            float4 b1 = *(const float4*)&sBC[t][4];
            float4 b2 = *(const float4*)&sBC[t][8];
            float4 b3 = *(const float4*)&sBC[t][12];
            float4 c0 = *(const float4*)&sBC[t][16];
            float4 c1 = *(const float4*)&sBC[t][20];
            float4 c2 = *(const float4*)&sBC[t][24];
            float4 c3 = *(const float4*)&sBC[t][28];
            float bv[16] = {b0.x,b0.y,b0.z,b0.w, b1.x,b1.y,b1.z,b1.w,
                            b2.x,b2.y,b2.z,b2.w, b3.x,b3.y,b3.z,b3.w};
            float cv[16] = {c0.x,c0.y,c0.z,c0.w, c1.x,c1.y,c1.z,c1.w,
                            c2.x,c2.y,c2.z,c2.w, c3.x,c3.y,c3.z,c3.w};
            float e1 = __expf(-dl);
            float E[16];
            POW_TREE(E, e1)
            float y = 0.f;
            #pragma unroll
            for (int s = 0; s < D_STATE; ++s) {
                h[s] = E[s] * h[s] + du * bv[s];
                y += h[s] * cv[s];
            }
            float sz = z / (1.f + __expf(-z));
            DL[(r0 + t) * D_INNER + d] = f2bf((y + uu * dp) * sz);
        }
    } else {
        for (int t = 0; t < CL; ++t) {
            float dl = bf2f(DL[(r0 + t) * D_INNER + d]);
            float uu = bf2f(XCbf[(r0 + t) * D_INNER + d]);
            float z  = bf2f(XZbf[(r0 + t) * XZLD + D_INNER + d]);
            float du = dl * uu;
            float4 b0 = *(const float4*)&sBC[t][0];
            float4 b1 = *(const float4*)&sBC[t][4];
            float4 b2 = *(const float4*)&sBC[t][8];
            float4 b3 = *(const float4*)&sBC[t][12];
            float4 c0 = *(const float4*)&sBC[t][16];
            float4 c1 = *(const float4*)&sBC[t][20];
            float4 c2 = *(const float4*)&sBC[t][24];
            float4 c3 = *(const float4*)&sBC[t][28];
            float bv[16] = {b0.x,b0.y,b0.z,b0.w, b1.x,b1.y,b1.z,b1.w,
                            b2.x,b2.y,b2.z,b2.w, b3.x,b3.y,b3.z,b3.w};
            float cv[16] = {c0.x,c0.y,c0.z,c0.w, c1.x,c1.y,c1.z,c1.w,
                            c2.x,c2.y,c2.z,c2.w, c3.x,c3.y,c3.z,c3.w};
            float y = 0.f;
            #pragma unroll
            for (int s = 0; s < D_STATE; ++s) {
                float e = __expf(dl * a[s]);
                h[s] = e * h[s] + du * bv[s];
                y += h[s] * cv[s];
            }
            float sz = z / (1.f + __expf(-z));
            DL[(r0 + t) * D_INNER + d] = f2bf((y + uu * dp) * sz);
        }
    }
}

// ---- path B scan variants (f32) ----
__global__ __launch_bounds__(SDB) void scan_part1(const float* __restrict__ XC,
    const float* __restrict__ XZ, const float* __restrict__ XDBL,
    const float* __restrict__ A_log, float* __restrict__ Psum, float* __restrict__ Ssum)
{
    __shared__ float sB[CL][16];
    int tid = threadIdx.x;
    int d = blockIdx.x * SDB + tid;
    int c = blockIdx.y, b = blockIdx.z;
    size_t r0 = (size_t)b * SEQ + (size_t)c * CL;

    #pragma unroll
    for (int i = 0; i < (CL * 4) / SDB; ++i) {
        int idx = tid + i * SDB;
        int t = idx >> 2, j = (idx & 3) * 4;
        *(float4*)&sB[t][j] = *(const float4*)(XDBL + (r0 + t) * XDIM + DT_RANK + j);
    }

    float a[D_STATE], S[D_STATE];
    #pragma unroll
    for (int i = 0; i < 4; ++i) {
        float4 v = *(const float4*)(A_log + (size_t)d * D_STATE + i * 4);
        a[i*4+0] = -__expf(v.x); a[i*4+1] = -__expf(v.y);
        a[i*4+2] = -__expf(v.z); a[i*4+3] = -__expf(v.w);
    }
    #pragma unroll
    for (int s = 0; s < D_STATE; ++s) S[s] = 0.f;
    float sumdl = 0.f;
    __syncthreads();

    for (int t = 0; t < CL; ++t) {
        float dl = XZ[(r0 + t) * XZLD + d];
        float uu = XC[(r0 + t) * D_INNER + d];
        float du = dl * uu;
        sumdl += dl;
        float4 b0 = *(const float4*)&sB[t][0];
        float4 b1 = *(const float4*)&sB[t][4];
        float4 b2 = *(const float4*)&sB[t][8];
        float4 b3 = *(const float4*)&sB[t][12];
        float bv[16] = {b0.x,b0.y,b0.z,b0.w, b1.x,b1.y,b1.z,b1.w,
                        b2.x,b2.y,b2.z,b2.w, b3.x,b3.y,b3.z,b3.w};
        #pragma unroll
        for (int s = 0; s < D_STATE; ++s) {
            float e = __expf(dl * a[s]);
            S[s] = e * S[s] + du * bv[s];
        }
    }

    size_t o = (((size_t)b * NC + c) * D_INNER + d) * D_STATE;
    #pragma unroll
    for (int i = 0; i < 4; ++i) {
        float4 p, s4;
        p.x = __expf(a[i*4+0] * sumdl); p.y = __expf(a[i*4+1] * sumdl);
        p.z = __expf(a[i*4+2] * sumdl); p.w = __expf(a[i*4+3] * sumdl);
        s4.x = S[i*4+0]; s4.y = S[i*4+1]; s4.z = S[i*4+2]; s4.w = S[i*4+3];
        *(float4*)(Psum + o + i * 4) = p;
        *(float4*)(Ssum + o + i * 4) = s4;
    }
}

__global__ __launch_bounds__(SDB) void scan_part2(const float* __restrict__ XC,
    float* __restrict__ XZ, const float* __restrict__ XDBL,
    const float* __restrict__ A_log, const float* __restrict__ Dp,
    const float* __restrict__ Hin)
{
    __shared__ float sBC[CL][32];
    int tid = threadIdx.x;
    int d = blockIdx.x * SDB + tid;
    int c = blockIdx.y, b = blockIdx.z;
    size_t r0 = (size_t)b * SEQ + (size_t)c * CL;

    #pragma unroll
    for (int i = 0; i < (CL * 8) / SDB; ++i) {
        int idx = tid + i * SDB;
        int t = idx >> 3, j = (idx & 7) * 4;
        *(float4*)&sBC[t][j] = *(const float4*)(XDBL + (r0 + t) * XDIM + DT_RANK + j);
    }

    float a[D_STATE], h[D_STATE];
    #pragma unroll
    for (int i = 0; i < 4; ++i) {
        float4 v = *(const float4*)(A_log + (size_t)d * D_STATE + i * 4);
        a[i*4+0] = -__expf(v.x); a[i*4+1] = -__expf(v.y);
        a[i*4+2] = -__expf(v.z); a[i*4+3] = -__expf(v.w);
    }
    size_t ho = (((size_t)b * NC + c) * D_INNER + d) * D_STATE;
    #pragma unroll
    for (int i = 0; i < 4; ++i) {
        float4 v = *(const float4*)(Hin + ho + i * 4);
        h[i*4+0] = v.x; h[i*4+1] = v.y; h[i*4+2] = v.z; h[i*4+3] = v.w;
    }
    float dp = Dp[d];
    __syncthreads();

    for (int t = 0; t < CL; ++t) {
        float dl = XZ[(r0 + t) * XZLD + d];
        float uu = XC[(r0 + t) * D_INNER + d];
        float z  = XZ[(r0 + t) * XZLD + D_INNER + d];
        float du = dl * uu;
        float4 b0 = *(const float4*)&sBC[t][0];
        float4 b1 = *(const float4*)&sBC[t][4];
        float4 b2 = *(const float4*)&sBC[t][8];
        float4 b3 = *(const float4*)&sBC[t][12];
        float4 c0 = *(const float4*)&sBC[t][16];
        float4 c1 = *(const float4*)&sBC[t][20];
        float4 c2 = *(const float4*)&sBC[t][24];
        float4 c3 = *(const float4*)&sBC[t][28];
        float bv[16] = {b0.x,b0.y,b0.z,b0.w, b1.x,b1.y,b1.z,b1.w,
                        b2.x,b2.y,b2.z,b2.w, b3.x,b3.y,b3.z,b3.w};
        float cv[16] = {c0.x,c0.y,c0.z,c0.w, c1.x,c1.y,c1.z,c1.w,
                        c2.x,c2.y,c2.z,c2.w, c3.x,c3.y,c3.z,c3.w};
        float y = 0.f;
        #pragma unroll
        for (int s = 0; s < D_STATE; ++s) {
            float e = __expf(dl * a[s]);
            h[s] = e * h[s] + du * bv[s];
            y += h[s] * cv[s];
        }
        float sz = z / (1.f + __expf(-z));
        XZ[(r0 + t) * XZLD + d] = (y + uu * dp) * sz;
    }
}

// ---------------- fallback sequential scan (path C) ----------------
__global__ __launch_bounds__(256) void scan_kernel2(const float* __restrict__ XC,
    float* __restrict__ XZ, const float* __restrict__ XDBL,
    const float* __restrict__ A_log, const float* __restrict__ Dp)
{
    int tid = threadIdx.x;
    int s  = tid & 15;
    int dd = tid >> 4;
    int d  = blockIdx.x * 16 + dd;
    int b  = blockIdx.y;

    float a  = -__expf(A_log[(size_t)d * D_STATE + s]);
    float h  = 0.f;
    float dp = Dp[d];
    const size_t rbase = (size_t)b * SEQ;

    for (int t = 0; t < SEQ; ++t) {
        size_t r = rbase + t;
        float dl = XZ[r * XZLD + d];
        float uu = XC[r * D_INNER + d];
        float z  = XZ[r * XZLD + D_INNER + d];
        float Bv = XDBL[r * XDIM + DT_RANK + s];
        float Cv = XDBL[r * XDIM + DT_RANK + D_STATE + s];
        float e  = __expf(dl * a);
        h = e * h + dl * uu * Bv;
        float y = h * Cv;
        y += __shfl_xor(y, 1);
        y += __shfl_xor(y, 2);
        y += __shfl_xor(y, 4);
        y += __shfl_xor(y, 8);
        if (s == 0) {
            float sz = z / (1.f + __expf(-z));
            XZ[r * XZLD + d] = (y + uu * dp) * sz;
        }
    }
}

extern "C" void kernel_launch(void* const* d_in, const int* in_sizes, int n_in,
                              void* d_out, int out_size, void* d_ws, size_t ws_size,
                              hipStream_t stream)
{
    const float* pe    = (const float*)d_in[0];
    const float* cond  = (const float*)d_in[1];
    const float* W_in  = (const float*)d_in[2];
    const float* cw    = (const float*)d_in[3];
    const float* cb    = (const float*)d_in[4];
    const float* W_x   = (const float*)d_in[5];
    const float* W_dt  = (const float*)d_in[6];
    const float* b_dt  = (const float*)d_in[7];
    const float* A_log = (const float*)d_in[8];
    const float* Dp    = (const float*)d_in[9];
    const float* W_out = (const float*)d_in[10];

    float* X = (float*)d_out;                          // [2048,1024] final output only

    // ---------------- path A layout (~86 MB) ----------------
    char* wsp = (char*)d_ws;
    unsigned short* XZbf = (unsigned short*)wsp;                       // [2048][4096] 16.8MB
    unsigned short* XCbf = (unsigned short*)(wsp + 16777216);          // [2048][2048] bf16 8.4MB
    unsigned short* XOUT = XCbf;                                       // l0 GEMM4 out [2048][1024] (same slot, serial lifetimes)
    float* XDBL  = (float*)(wsp + 33554432);                           // [2048][96]   0.8MB
    unsigned short* BF0   = (unsigned short*)(wsp + 34340864);         // [2048][2048] 8.4MB (x/delta/out)
    unsigned short* dtbf  = (unsigned short*)(wsp + 42729472);         // [2048][64]   0.26MB
    unsigned short* WINbf = (unsigned short*)(wsp + 42991616);         // 2x[4096][1024] 16.8MB
    unsigned short* WOUTbf= (unsigned short*)(wsp + 59768832);         // 2x[1024][2048] 8.4MB
    unsigned short* WDTbf = (unsigned short*)(wsp + 68157440);         // 2x[2048][64]  0.52MB
    float* SCR   = (float*)(wsp + 68681728);                           // 16.8MB scratch (GEMM2 partials + scan sums)
    size_t need_A = 68681728 + 16777216;                               // ~85.5MB

    // ---------------- path B layout (round-6, ~68MB) ----------------
    float* XZb   = (float*)d_ws;
    float* XCb   = XZb + (size_t)ROWS * XZLD;
    float* XDBLb = XCb + (size_t)ROWS * D_INNER;
    void* rest = (void*)(XDBLb + (size_t)ROWS * XDIM);
    unsigned short* Abf = (unsigned short*)rest;
    unsigned short* Bbf = Abf + (size_t)ROWS * D_INNER;
    float* PpartB = (float*)rest;
    float* PsumB  = (float*)rest;
    float* SsumB  = PsumB + (size_t)BATCH * NC * D_INNER * D_STATE;
    size_t need_B = ((size_t)ROWS * XZLD + (size_t)ROWS * D_INNER + (size_t)ROWS * XDIM) * 4
                  + ((size_t)ROWS * D_INNER + (size_t)ROWS * D_INNER) * 2;

    if (ws_size >= need_A) {
        // =========================== PATH A ===========================
        float* Psum = SCR;                                             // 4.2MB (NC=16)
        float* Ssum = SCR + (size_t)BATCH * NC * D_INNER * D_STATE;    // 4.2MB

        // one-time: all weights + x -> bf16 in ONE dispatch
        conv_wall<<<(WN1 + WN2 + WN3 + WN4 + 255) / 256, 256, 0, stream>>>(
            W_in, W_out, W_dt, pe, cond, WINbf, WOUTbf, WDTbf, BF0);

        for (int l = 0; l < NLAYERS; ++l) {
            const unsigned short* WINl  = WINbf  + (size_t)l * 2 * D_INNER * D_MODEL;
            const unsigned short* WOUTl = WOUTbf + (size_t)l * D_MODEL * D_INNER;
            const unsigned short* WDTl  = WDTbf  + (size_t)l * D_INNER * DT_RANK;
            const float* W_x_l   = W_x   + (size_t)l * XDIM * D_INNER;
            const float* cw_l    = cw    + (size_t)l * D_INNER * 4;
            const float* cb_l    = cb    + (size_t)l * D_INNER;
            const float* b_dt_l  = b_dt  + (size_t)l * D_INNER;
            const float* A_log_l = A_log + (size_t)l * D_INNER * D_STATE;
            const float* Dp_l    = Dp    + (size_t)l * D_INNER;
            const unsigned short* xin = (l == 0) ? BF0 : XOUT;   // layer input x (bf16)

            // GEMM1: xz(bf16) = x(bf16) @ W_in^T
            gemm_bf16_nt_bfout<<<dim3(2 * D_INNER / GBN, ROWS / GBM), 256, 0, stream>>>(
                xin, WINl, XZbf, ROWS, 2 * D_INNER, D_MODEL, XZLD);
            // FUSED conv+silu + GEMM2 split-K (xc -> XCbf bf16, partials -> SCR)
            gemm2_fused<<<dim3(ROWS / G2_ROWS, G2_KS), 256, 0, stream>>>(
                XZbf, cw_l, cb_l, W_x_l, XCbf, SCR);
            gemm2_reduce<<<(ROWS * XDIM / 4 + 255) / 256, 256, 0, stream>>>(SCR, XDBL, dtbf);
            // GEMM3: delta(bf16 dense) = softplus(dt @ W_dt^T + b_dt) -> BF0
            gemm_bf16_sp_bfout<<<dim3(D_INNER / GBN, ROWS / GBM), 256, 0, stream>>>(
                dtbf, WDTl, BF0, ROWS, D_INNER, DT_RANK, D_INNER, b_dt_l);
            // chunked scan (out bf16 in place -> GEMM4 A)
            scan_part1b<<<dim3(D_INNER / SDB, NC, BATCH), SDB, 0, stream>>>(
                XCbf, BF0, XDBL, A_log_l, Psum, Ssum);
            scan_prefix<<<BATCH * D_INNER * D_STATE / 256, 256, 0, stream>>>(Psum, Ssum);
            scan_part2b<<<dim3(D_INNER / SDB, NC, BATCH), SDB, 0, stream>>>(
                XCbf, BF0, XZbf, XDBL, A_log_l, Dp_l, Psum);
            // GEMM4: x = out @ W_out^T, 128x64 tile, no split-K
            //   l0 -> bf16 XOUT (next-layer GEMM1 A);  l1 -> f32 X (d_out)
            gemm_bf16_nt64<<<dim3(D_MODEL / G4BN, ROWS / GBM), 256, 0, stream>>>(
                BF0, D_INNER, WOUTl, D_INNER,
                (l < NLAYERS - 1) ? XOUT : nullptr,
                (l == NLAYERS - 1) ? X : nullptr,
                ROWS, D_MODEL, D_INNER);
        }
    } else if (ws_size >= need_B) {
        // =========================== PATH B (round-6) ===========================
        add_pe_kernel<<<ROWS * D_MODEL / 4 / 256, 256, 0, stream>>>(pe, cond, X);
        for (int l = 0; l < NLAYERS; ++l) {
            const float* W_in_l  = W_in  + (size_t)l * 2 * D_INNER * D_MODEL;
            const float* W_out_l = W_out + (size_t)l * D_MODEL * D_INNER;
            const float* W_x_l   = W_x   + (size_t)l * XDIM * D_INNER;
            const float* W_dt_l  = W_dt  + (size_t)l * D_INNER * DT_RANK;
            const float* b_dt_l  = b_dt  + (size_t)l * D_INNER;
            const float* A_log_l = A_log + (size_t)l * D_INNER * D_STATE;
            const float* Dp_l    = Dp    + (size_t)l * D_INNER;

            conv_bf16_dense<<<(ROWS * D_MODEL / 4 + 255) / 256, 256, 0, stream>>>(X, Abf, ROWS * D_MODEL / 4);
            conv_bf16_dense<<<(2 * D_INNER * D_MODEL / 4 + 255) / 256, 256, 0, stream>>>(W_in_l, Bbf, 2 * D_INNER * D_MODEL / 4);
            gemm_bf16_nt<<<dim3(2 * D_INNER / GBN, ROWS / GBM), 256, 0, stream>>>(
                Abf, Bbf, XZb, ROWS, 2 * D_INNER, D_MODEL, XZLD, nullptr, 0);
            conv_silu_kernel<<<ROWS * (D_INNER / 4) / 256, 256, 0, stream>>>(
                XZb, cw + (size_t)l * D_INNER * 4, cb + (size_t)l * D_INNER, XCb);
            gemm2_splitk<<<dim3(ROWS / G2_ROWS, G2_KS), 256, 0, stream>>>(XCb, W_x_l, PpartB);
            gemm2_reduce<<<(ROWS * XDIM / 4 + 255) / 256, 256, 0, stream>>>(PpartB, XDBLb, nullptr);
            conv_bf16_dtcols<<<(ROWS * DT_RANK / 4 + 255) / 256, 256, 0, stream>>>(XDBLb, Abf);
            conv_bf16_dense<<<(D_INNER * DT_RANK / 4 + 255) / 256, 256, 0, stream>>>(W_dt_l, Bbf, D_INNER * DT_RANK / 4);
            gemm_bf16_nt<<<dim3(D_INNER / GBN, ROWS / GBM), 256, 0, stream>>>(
                Abf, Bbf, XZb, ROWS, D_INNER, DT_RANK, XZLD, b_dt_l, 1);
            scan_part1<<<dim3(D_INNER / SDB, NC, BATCH), SDB, 0, stream>>>(
                XCb, XZb, XDBLb, A_log_l, PsumB, SsumB);
            scan_prefix<<<BATCH * D_INNER * D_STATE / 256, 256, 0, stream>>>(PsumB, SsumB);
            scan_part2<<<dim3(D_INNER / SDB, NC, BATCH), SDB, 0, stream>>>(
                XCb, XZb, XDBLb, A_log_l, Dp_l, PsumB);
            conv_bf16_strided<<<(ROWS * D_INNER / 4 + 255) / 256, 256, 0, stream>>>(
                XZb, XZLD, D_INNER, Abf, ROWS * D_INNER / 4);
            conv_bf16_dense<<<(D_MODEL * D_INNER / 4 + 255) / 256, 256, 0, stream>>>(W_out_l, Bbf, D_MODEL * D_INNER / 4);
            gemm_bf16_nt<<<dim3(D_MODEL / GBN, ROWS / GBM), 256, 0, stream>>>(
                Abf, Bbf, X, ROWS, D_MODEL, D_INNER, D_MODEL, nullptr, 0);
        }
    } else {
        // =========================== PATH C (fp32) ===========================
        add_pe_kernel<<<ROWS * D_MODEL / 4 / 256, 256, 0, stream>>>(pe, cond, X);
        for (int l = 0; l < NLAYERS; ++l) {
            gemm_nt<<<dim3(2 * D_INNER / BN, ROWS / BM), 256, 0, stream>>>(
                X, D_MODEL, W_in + (size_t)l * 2 * D_INNER * D_MODEL, D_MODEL,
                XZb, XZLD, ROWS, 2 * D_INNER, D_MODEL, nullptr, 0);
            conv_silu_kernel<<<ROWS * (D_INNER / 4) / 256, 256, 0, stream>>>(
                XZb, cw + (size_t)l * D_INNER * 4, cb + (size_t)l * D_INNER, XCb);
            gemm_nt<<<dim3((XDIM + BN - 1) / BN, ROWS / BM), 256, 0, stream>>>(
                XCb, D_INNER, W_x + (size_t)l * XDIM * D_INNER, D_INNER,
                XDBLb, XDIM, ROWS, XDIM, D_INNER, nullptr, 0);
            gemm_nt<<<dim3(D_INNER / BN, ROWS / BM), 256, 0, stream>>>(
                XDBLb, XDIM, W_dt + (size_t)l * D_INNER * DT_RANK, DT_RANK,
                XZb, XZLD, ROWS, D_INNER, DT_RANK, b_dt + (size_t)l * D_INNER, 1);
            scan_kernel2<<<dim3(D_INNER / 16, BATCH), 256, 0, stream>>>(
                XCb, XZb, XDBLb, A_log + (size_t)l * D_INNER * D_STATE, Dp + (size_t)l * D_INNER);
            gemm_nt<<<dim3(D_MODEL / BN, ROWS / BM), 256, 0, stream>>>(
                XZb, XZLD, W_out + (size_t)l * D_MODEL * D_INNER, D_INNER,
                X, D_MODEL, ROWS, D_MODEL, D_INNER, nullptr, 0);
        }
    }
}

// Round 13
// 327.343 us; speedup vs baseline: 1.1044x; 1.1044x over previous
//
#include <hip/hip_runtime.h>
#include <math.h>

#define D_MODEL 1024
#define D_INNER 2048
#define D_STATE 16
#define DT_RANK 64
#define SEQ 1024
#define BATCH 2
#define NLAYERS 2
#define ROWS (BATCH*SEQ)      // 2048
#define XDIM 96               // dt_rank + 2*d_state
#define XZLD (2*D_INNER)      // 4096

// chunked scan geometry (CL*NC == SEQ) — CL=32/NC=32 is the measured-best config
#define NC 32
#define CL 32
#define SDB 256

// GEMM2 split-K geometry
#define G2_ROWS 64
#define G2_KC 128
#define G2_BK 32
#define G2_KS (D_INNER / G2_KC)

typedef short bf16x8 __attribute__((ext_vector_type(8)));
typedef float f32x4  __attribute__((ext_vector_type(4)));

// ---------------- helpers ----------------
__device__ __forceinline__ unsigned short f2bf(float f) {
    union { float f; unsigned int u; } v; v.f = f;
    unsigned int u = v.u;
    return (unsigned short)((u + 0x7FFFu + ((u >> 16) & 1u)) >> 16);   // RNE
}
__device__ __forceinline__ float bf2f(unsigned short u) {
    union { unsigned int i; float f; } v; v.i = ((unsigned int)u) << 16; return v.f;
}

__device__ __forceinline__ void gload_lds16(const void* g, void* s) {
    __builtin_amdgcn_global_load_lds((const __attribute__((address_space(1))) void*)g,
                                     (__attribute__((address_space(3))) void*)s, 16, 0, 0);
}

// e1^(s+1) for s=0..15, depth-4 multiply tree
#define POW_TREE(E, e1)                                                         \
    E[0] = e1;          E[1] = e1 * e1;   E[2] = E[1] * e1;  E[3] = E[1] * E[1];\
    E[4] = E[3] * E[0]; E[5] = E[3] * E[1]; E[6] = E[3] * E[2]; E[7] = E[3] * E[3];\
    E[8] = E[7] * E[0]; E[9] = E[7] * E[1]; E[10] = E[7] * E[2]; E[11] = E[7] * E[3];\
    E[12] = E[7] * E[4]; E[13] = E[7] * E[5]; E[14] = E[7] * E[6]; E[15] = E[7] * E[7];

// ---------------- x = pe + condition (f32 out; paths B/C) ----------------
__global__ __launch_bounds__(256) void add_pe_kernel(const float* __restrict__ pe,
    const float* __restrict__ cond, float* __restrict__ X)
{
    int i = blockIdx.x * 256 + threadIdx.x;
    int total = ROWS * D_MODEL / 4;
    if (i >= total) return;
    int row  = i / (D_MODEL / 4);
    int l    = row & (SEQ - 1);
    int col4 = i - row * (D_MODEL / 4);
    float4 p = reinterpret_cast<const float4*>(pe)[l * (D_MODEL / 4) + col4];
    float4 c = reinterpret_cast<const float4*>(cond)[i];
    float4 r; r.x = p.x + c.x; r.y = p.y + c.y; r.z = p.z + c.z; r.w = p.w + c.w;
    reinterpret_cast<float4*>(X)[i] = r;
}

// ---------------- f32 -> bf16 conversions ----------------
__global__ __launch_bounds__(256) void conv_bf16_dense(const float* __restrict__ src,
    unsigned short* __restrict__ dst, int n4)
{
    int i = blockIdx.x * 256 + threadIdx.x;
    if (i >= n4) return;
    float4 v = reinterpret_cast<const float4*>(src)[i];
    ushort4 o; o.x = f2bf(v.x); o.y = f2bf(v.y); o.z = f2bf(v.z); o.w = f2bf(v.w);
    reinterpret_cast<ushort4*>(dst)[i] = o;
}

// one dispatch: all three weight tensors -> bf16 AND x = pe+cond -> bf16 (path A pre-loop)
#define WN1 (NLAYERS * 2 * D_INNER * D_MODEL / 4)
#define WN2 (NLAYERS * D_MODEL * D_INNER / 4)
#define WN3 (NLAYERS * D_INNER * DT_RANK / 4)
#define WN4 (ROWS * D_MODEL / 4)
__global__ __launch_bounds__(256) void conv_wall(const float* __restrict__ Win,
    const float* __restrict__ Wout, const float* __restrict__ Wdt,
    const float* __restrict__ pe, const float* __restrict__ cond,
    unsigned short* __restrict__ WINbf, unsigned short* __restrict__ WOUTbf,
    unsigned short* __restrict__ WDTbf, unsigned short* __restrict__ Xbf)
{
    int i = blockIdx.x * 256 + threadIdx.x;
    if (i < WN1) {
        float4 v = reinterpret_cast<const float4*>(Win)[i];
        ushort4 o; o.x = f2bf(v.x); o.y = f2bf(v.y); o.z = f2bf(v.z); o.w = f2bf(v.w);
        reinterpret_cast<ushort4*>(WINbf)[i] = o;
    } else if (i < WN1 + WN2) {
        int j = i - WN1;
        float4 v = reinterpret_cast<const float4*>(Wout)[j];
        ushort4 o; o.x = f2bf(v.x); o.y = f2bf(v.y); o.z = f2bf(v.z); o.w = f2bf(v.w);
        reinterpret_cast<ushort4*>(WOUTbf)[j] = o;
    } else if (i < WN1 + WN2 + WN3) {
        int j = i - WN1 - WN2;
        float4 v = reinterpret_cast<const float4*>(Wdt)[j];
        ushort4 o; o.x = f2bf(v.x); o.y = f2bf(v.y); o.z = f2bf(v.z); o.w = f2bf(v.w);
        reinterpret_cast<ushort4*>(WDTbf)[j] = o;
    } else if (i < WN1 + WN2 + WN3 + WN4) {
        int j = i - WN1 - WN2 - WN3;
        int row  = j / (D_MODEL / 4);
        int l    = row & (SEQ - 1);
        int col4 = j - row * (D_MODEL / 4);
        float4 p = reinterpret_cast<const float4*>(pe)[l * (D_MODEL / 4) + col4];
        float4 c = reinterpret_cast<const float4*>(cond)[j];
        ushort4 o;
        o.x = f2bf(p.x + c.x); o.y = f2bf(p.y + c.y);
        o.z = f2bf(p.z + c.z); o.w = f2bf(p.w + c.w);
        reinterpret_cast<ushort4*>(Xbf)[j] = o;
    }
}

__global__ __launch_bounds__(256) void conv_bf16_strided(const float* __restrict__ src,
    int ld, int cols, unsigned short* __restrict__ dst, int total4)
{
    int i = blockIdx.x * 256 + threadIdx.x;
    if (i >= total4) return;
    int c4  = cols / 4;
    int row = i / c4;
    int col = (i - row * c4) * 4;
    float4 v = *reinterpret_cast<const float4*>(src + (size_t)row * ld + col);
    ushort4 o; o.x = f2bf(v.x); o.y = f2bf(v.y); o.z = f2bf(v.z); o.w = f2bf(v.w);
    *reinterpret_cast<ushort4*>(dst + (size_t)row * cols + col) = o;
}

__global__ __launch_bounds__(256) void conv_bf16_dtcols(const float* __restrict__ XDBL,
    unsigned short* __restrict__ dst)
{
    int i = blockIdx.x * 256 + threadIdx.x;
    if (i >= ROWS * DT_RANK / 4) return;
    int m  = i >> 4;
    int c4 = (i & 15) * 4;
    float4 v = *reinterpret_cast<const float4*>(XDBL + (size_t)m * XDIM + c4);
    ushort4 o; o.x = f2bf(v.x); o.y = f2bf(v.y); o.z = f2bf(v.z); o.w = f2bf(v.w);
    *reinterpret_cast<ushort4*>(dst + (size_t)m * DT_RANK + c4) = o;
}

// ================= bf16 MFMA NT GEMM family =================
#define GBM 128
#define GBN 128
#define GBK 64

#define GEMM_STAGE(Ap, Bp, lda, ldb, koff)                                      \
    _Pragma("unroll")                                                           \
    for (int i_ = 0; i_ < 4; ++i_) {                                            \
        int off_ = w * 4096 + i_ * 1024 + l * 16;                               \
        int row_ = off_ >> 7;                                                   \
        int col_ = (off_ & 127) >> 1;                                           \
        gload_lds16(Ap + (size_t)(m0 + row_) * (lda) + (koff) + col_,           \
                    (char*)As + w * 4096 + i_ * 1024);                          \
    }                                                                           \
    _Pragma("unroll")                                                           \
    for (int i_ = 0; i_ < 4; ++i_) {                                            \
        int off_ = w * 4096 + i_ * 1024 + l * 16;                               \
        int row_ = off_ >> 7;                                                   \
        int col_ = (off_ & 127) >> 1;                                           \
        gload_lds16(Bp + (size_t)(n0 + row_) * (ldb) + (koff) + col_,           \
                    (char*)Bs + w * 4096 + i_ * 1024);                          \
    }

#define GEMM_MFMA_STEP                                                          \
    _Pragma("unroll")                                                           \
    for (int kk = 0; kk < 2; ++kk) {                                            \
        bf16x8 af[4], bfr[4];                                                   \
        _Pragma("unroll")                                                       \
        for (int m = 0; m < 4; ++m)                                             \
            af[m] = *(const bf16x8*)&As[(wr * 64 + m * 16 + fr) * GBK + kk * 32 + fq * 8]; \
        _Pragma("unroll")                                                       \
        for (int n = 0; n < 4; ++n)                                             \
            bfr[n] = *(const bf16x8*)&Bs[(wc * 64 + n * 16 + fr) * GBK + kk * 32 + fq * 8]; \
        _Pragma("unroll")                                                       \
        for (int m = 0; m < 4; ++m)                                             \
            _Pragma("unroll")                                                   \
            for (int n = 0; n < 4; ++n)                                         \
                acc[m][n] = __builtin_amdgcn_mfma_f32_16x16x32_bf16(af[m], bfr[n], acc[m][n], 0, 0, 0); \
    }

// f32 out, optional softplus epilogue (path B)
__global__ __launch_bounds__(256) void gemm_bf16_nt(const unsigned short* __restrict__ A,
    const unsigned short* __restrict__ B, float* __restrict__ C,
    int M, int N, int K, int ldc, const float* __restrict__ bias, int epilogue)
{
    __shared__ unsigned short As[GBM * GBK];
    __shared__ unsigned short Bs[GBN * GBK];
    int tid = threadIdx.x;
    int w = tid >> 6, l = tid & 63;
    int wr = w >> 1, wc = w & 1;
    int m0 = blockIdx.y * GBM, n0 = blockIdx.x * GBN;

    f32x4 acc[4][4];
    #pragma unroll
    for (int m = 0; m < 4; ++m)
        #pragma unroll
        for (int n = 0; n < 4; ++n) acc[m][n] = (f32x4){0.f, 0.f, 0.f, 0.f};
    int fr = l & 15, fq = l >> 4;

    for (int k0 = 0; k0 < K; k0 += GBK) {
        GEMM_STAGE(A, B, K, K, k0)
        __syncthreads();
        GEMM_MFMA_STEP
        __syncthreads();
    }

    #pragma unroll
    for (int m = 0; m < 4; ++m)
        #pragma unroll
        for (int n = 0; n < 4; ++n) {
            int col = n0 + wc * 64 + n * 16 + fr;
            #pragma unroll
            for (int j = 0; j < 4; ++j) {
                int row = m0 + wr * 64 + m * 16 + fq * 4 + j;
                float v = acc[m][n][j];
                if (epilogue == 1) {
                    v += bias[col];
                    v = fmaxf(v, 0.f) + log1pf(__expf(-fabsf(v)));
                }
                C[(size_t)row * ldc + col] = v;
            }
        }
}

// bf16 out, no epilogue (path A GEMM1)
__global__ __launch_bounds__(256) void gemm_bf16_nt_bfout(const unsigned short* __restrict__ A,
    const unsigned short* __restrict__ B, unsigned short* __restrict__ C,
    int M, int N, int K, int ldc)
{
    __shared__ unsigned short As[GBM * GBK];
    __shared__ unsigned short Bs[GBN * GBK];
    int tid = threadIdx.x;
    int w = tid >> 6, l = tid & 63;
    int wr = w >> 1, wc = w & 1;
    int m0 = blockIdx.y * GBM, n0 = blockIdx.x * GBN;

    f32x4 acc[4][4];
    #pragma unroll
    for (int m = 0; m < 4; ++m)
        #pragma unroll
        for (int n = 0; n < 4; ++n) acc[m][n] = (f32x4){0.f, 0.f, 0.f, 0.f};
    int fr = l & 15, fq = l >> 4;

    for (int k0 = 0; k0 < K; k0 += GBK) {
        GEMM_STAGE(A, B, K, K, k0)
        __syncthreads();
        GEMM_MFMA_STEP
        __syncthreads();
    }

    #pragma unroll
    for (int m = 0; m < 4; ++m)
        #pragma unroll
        for (int n = 0; n < 4; ++n) {
            int col = n0 + wc * 64 + n * 16 + fr;
            #pragma unroll
            for (int j = 0; j < 4; ++j) {
                int row = m0 + wr * 64 + m * 16 + fq * 4 + j;
                C[(size_t)row * ldc + col] = f2bf(acc[m][n][j]);
            }
        }
}

// softplus + bf16 out (GEMM3 path A)
__global__ __launch_bounds__(256) void gemm_bf16_sp_bfout(const unsigned short* __restrict__ A,
    const unsigned short* __restrict__ B, unsigned short* __restrict__ C,
    int M, int N, int K, int ldc, const float* __restrict__ bias)
{
    __shared__ unsigned short As[GBM * GBK];
    __shared__ unsigned short Bs[GBN * GBK];
    int tid = threadIdx.x;
    int w = tid >> 6, l = tid & 63;
    int wr = w >> 1, wc = w & 1;
    int m0 = blockIdx.y * GBM, n0 = blockIdx.x * GBN;

    f32x4 acc[4][4];
    #pragma unroll
    for (int m = 0; m < 4; ++m)
        #pragma unroll
        for (int n = 0; n < 4; ++n) acc[m][n] = (f32x4){0.f, 0.f, 0.f, 0.f};
    int fr = l & 15, fq = l >> 4;

    for (int k0 = 0; k0 < K; k0 += GBK) {
        GEMM_STAGE(A, B, K, K, k0)
        __syncthreads();
        GEMM_MFMA_STEP
        __syncthreads();
    }

    #pragma unroll
    for (int m = 0; m < 4; ++m)
        #pragma unroll
        for (int n = 0; n < 4; ++n) {
            int col = n0 + wc * 64 + n * 16 + fr;
            float bv = bias[col];
            #pragma unroll
            for (int j = 0; j < 4; ++j) {
                int row = m0 + wr * 64 + m * 16 + fq * 4 + j;
                float v = acc[m][n][j] + bv;
                v = fmaxf(v, 0.f) + log1pf(__expf(-fabsf(v)));   // stable softplus
                C[(size_t)row * ldc + col] = f2bf(v);
            }
        }
}

// ---------------- GEMM4 path A: 128x64 tile, no split-K, dual output ----------------
#define G4BN 64
__global__ __launch_bounds__(256) void gemm_bf16_nt64(const unsigned short* __restrict__ A, int lda,
    const unsigned short* __restrict__ B, int ldb,
    unsigned short* __restrict__ Cbf, float* __restrict__ Cf,
    int M, int N, int K)
{
    __shared__ unsigned short As[GBM * GBK];   // 16 KB
    __shared__ unsigned short Bs[G4BN * GBK];  // 8 KB
    int tid = threadIdx.x;
    int w = tid >> 6, l = tid & 63;
    int wr = w >> 1, wc = w & 1;               // 2x2 waves over 128x64
    int m0 = blockIdx.y * GBM, n0 = blockIdx.x * G4BN;

    f32x4 acc[4][2];
    #pragma unroll
    for (int m = 0; m < 4; ++m)
        #pragma unroll
        for (int n = 0; n < 2; ++n) acc[m][n] = (f32x4){0.f, 0.f, 0.f, 0.f};
    int fr = l & 15, fq = l >> 4;

    for (int k0 = 0; k0 < K; k0 += GBK) {
        #pragma unroll
        for (int i_ = 0; i_ < 4; ++i_) {
            int off_ = w * 4096 + i_ * 1024 + l * 16;
            int row_ = off_ >> 7;
            int col_ = (off_ & 127) >> 1;
            gload_lds16(A + (size_t)(m0 + row_) * lda + k0 + col_,
                        (char*)As + w * 4096 + i_ * 1024);
        }
        #pragma unroll
        for (int i_ = 0; i_ < 2; ++i_) {
            int off_ = w * 2048 + i_ * 1024 + l * 16;
            int row_ = off_ >> 7;
            int col_ = (off_ & 127) >> 1;
            gload_lds16(B + (size_t)(n0 + row_) * ldb + k0 + col_,
                        (char*)Bs + w * 2048 + i_ * 1024);
        }
        __syncthreads();
        #pragma unroll
        for (int kk = 0; kk < 2; ++kk) {
            bf16x8 af[4], bfr[2];
            #pragma unroll
            for (int m = 0; m < 4; ++m)
                af[m] = *(const bf16x8*)&As[(wr * 64 + m * 16 + fr) * GBK + kk * 32 + fq * 8];
            #pragma unroll
            for (int n = 0; n < 2; ++n)
                bfr[n] = *(const bf16x8*)&Bs[(wc * 32 + n * 16 + fr) * GBK + kk * 32 + fq * 8];
            #pragma unroll
            for (int m = 0; m < 4; ++m)
                #pragma unroll
                for (int n = 0; n < 2; ++n)
                    acc[m][n] = __builtin_amdgcn_mfma_f32_16x16x32_bf16(af[m], bfr[n], acc[m][n], 0, 0, 0);
        }
        __syncthreads();
    }

    #pragma unroll
    for (int m = 0; m < 4; ++m)
        #pragma unroll
        for (int n = 0; n < 2; ++n) {
            int col = n0 + wc * 32 + n * 16 + fr;
            #pragma unroll
            for (int j = 0; j < 4; ++j) {
                int row = m0 + wr * 64 + m * 16 + fq * 4 + j;
                float v = acc[m][n][j];
                if (Cbf) Cbf[(size_t)row * N + col] = f2bf(v);
                else     Cf[(size_t)row * N + col] = v;
            }
        }
}

// ---------------- FUSED conv+silu + GEMM2 split-K (path A) ----------------
__global__ __launch_bounds__(256) void gemm2_fused(const unsigned short* __restrict__ XZbf,
    const float* __restrict__ cw, const float* __restrict__ cb,
    const float* __restrict__ B, unsigned short* __restrict__ XCbf,
    float* __restrict__ P)
{
    __shared__ float Axc[G2_KC][68];           // 34.8 KB
    __shared__ float Bs[G2_BK][XDIM + 1];      // 12.1 KB
    int tid = threadIdx.x;
    int m0 = blockIdx.x * G2_ROWS;
    int kc = blockIdx.y;
    int k0 = kc * G2_KC;

    // ---- phase 1: conv+silu ----
    {
        int d_loc = tid & 127;
        int d     = k0 + d_loc;
        int r0    = m0 + (tid >> 7) * 32;
        float4 wv = *(const float4*)(cw + (size_t)d * 4);
        float cbv = cb[d];
        int l0 = r0 & (SEQ - 1);
        float u3 = (l0 >= 3) ? bf2f(XZbf[(size_t)(r0 - 3) * XZLD + d]) : 0.f;
        float u2 = (l0 >= 2) ? bf2f(XZbf[(size_t)(r0 - 2) * XZLD + d]) : 0.f;
        float u1 = (l0 >= 1) ? bf2f(XZbf[(size_t)(r0 - 1) * XZLD + d]) : 0.f;
        int rl0 = r0 - m0;
        #pragma unroll 4
        for (int t = 0; t < 32; ++t) {
            float u0 = bf2f(XZbf[(size_t)(r0 + t) * XZLD + d]);
            float v = cbv + wv.x * u3 + wv.y * u2 + wv.z * u1 + wv.w * u0;
            v = v / (1.f + __expf(-v));        // silu
            Axc[d_loc][rl0 + t] = v;
            XCbf[(size_t)(r0 + t) * D_INNER + d] = f2bf(v);
            u3 = u2; u2 = u1; u1 = u0;
        }
    }
    __syncthreads();

    // ---- phase 2: GEMM ----
    int rg = tid >> 4;
    int cg = tid & 15;
    float acc[4][6];
    #pragma unroll
    for (int i = 0; i < 4; ++i)
        #pragma unroll
        for (int j = 0; j < 6; ++j) acc[i][j] = 0.f;

    for (int kb = 0; kb < G2_KC; kb += G2_BK) {
        {
            #pragma unroll
            for (int i = 0; i < 3; ++i) {
                int idx = tid + i * 256;
                int col = idx >> 3;
                int kk  = (idx & 7) * 4;
                float4 v = *(const float4*)(B + (size_t)col * D_INNER + k0 + kb + kk);
                Bs[kk + 0][col] = v.x;
                Bs[kk + 1][col] = v.y;
                Bs[kk + 2][col] = v.z;
                Bs[kk + 3][col] = v.w;
            }
        }
        __syncthreads();
        #pragma unroll
        for (int k = 0; k < G2_BK; ++k) {
            float4 a  = *(const float4*)&Axc[kb + k][rg * 4];
            float2 b0 = *(const float2*)&Bs[k][cg * 6];
            float2 b1 = *(const float2*)&Bs[k][cg * 6 + 2];
            float2 b2 = *(const float2*)&Bs[k][cg * 6 + 4];
            float av[4] = {a.x, a.y, a.z, a.w};
            float bv[6] = {b0.x, b0.y, b1.x, b1.y, b2.x, b2.y};
            #pragma unroll
            for (int i = 0; i < 4; ++i)
                #pragma unroll
                for (int j = 0; j < 6; ++j) acc[i][j] += av[i] * bv[j];
        }
        __syncthreads();
    }

    #pragma unroll
    for (int i = 0; i < 4; ++i)
        #pragma unroll
        for (int j = 0; j < 6; ++j)
            P[((size_t)kc * ROWS + m0 + rg * 4 + i) * XDIM + cg * 6 + j] = acc[i][j];
}

// ---------------- GEMM2 split-K (f32, path B) ----------------
__global__ __launch_bounds__(256) void gemm2_splitk(const float* __restrict__ A,
    const float* __restrict__ B, float* __restrict__ P)
{
    __shared__ float As[G2_BK][G2_ROWS];
    __shared__ float Bs[G2_BK][XDIM + 1];
    int tid = threadIdx.x;
    int m0 = blockIdx.x * G2_ROWS;
    int kc = blockIdx.y;
    int k0 = kc * G2_KC;

    int rg = tid >> 4;
    int cg = tid & 15;
    float acc[4][6];
    #pragma unroll
    for (int i = 0; i < 4; ++i)
        #pragma unroll
        for (int j = 0; j < 6; ++j) acc[i][j] = 0.f;

    for (int kb = 0; kb < G2_KC; kb += G2_BK) {
        {
            int row = tid & 63;
            int kk  = (tid >> 6) * 4;
            #pragma unroll
            for (int i = 0; i < 2; ++i) {
                float4 v = *(const float4*)(A + (size_t)(m0 + row) * D_INNER + k0 + kb + kk + i * 16);
                As[kk + i * 16 + 0][row] = v.x;
                As[kk + i * 16 + 1][row] = v.y;
                As[kk + i * 16 + 2][row] = v.z;
                As[kk + i * 16 + 3][row] = v.w;
            }
        }
        {
            #pragma unroll
            for (int i = 0; i < 3; ++i) {
                int idx = tid + i * 256;
                int col = idx >> 3;
                int kk  = (idx & 7) * 4;
                float4 v = *(const float4*)(B + (size_t)col * D_INNER + k0 + kb + kk);
                Bs[kk + 0][col] = v.x;
                Bs[kk + 1][col] = v.y;
                Bs[kk + 2][col] = v.z;
                Bs[kk + 3][col] = v.w;
            }
        }
        __syncthreads();
        #pragma unroll
        for (int k = 0; k < G2_BK; ++k) {
            float4 a  = *(const float4*)&As[k][rg * 4];
            float2 b0 = *(const float2*)&Bs[k][cg * 6];
            float2 b1 = *(const float2*)&Bs[k][cg * 6 + 2];
            float2 b2 = *(const float2*)&Bs[k][cg * 6 + 4];
            float av[4] = {a.x, a.y, a.z, a.w};
            float bv[6] = {b0.x, b0.y, b1.x, b1.y, b2.x, b2.y};
            #pragma unroll
            for (int i = 0; i < 4; ++i)
                #pragma unroll
                for (int j = 0; j < 6; ++j) acc[i][j] += av[i] * bv[j];
        }
        __syncthreads();
    }

    #pragma unroll
    for (int i = 0; i < 4; ++i)
        #pragma unroll
        for (int j = 0; j < 6; ++j)
            P[((size_t)kc * ROWS + m0 + rg * 4 + i) * XDIM + cg * 6 + j] = acc[i][j];
}

// reduce; optionally emit dt columns as bf16
__global__ __launch_bounds__(256) void gemm2_reduce(const float* __restrict__ P,
    float* __restrict__ XDBLo, unsigned short* __restrict__ dtbf)
{
    int i = blockIdx.x * 256 + threadIdx.x;
    if (i >= ROWS * XDIM / 4) return;
    float4 acc = make_float4(0.f, 0.f, 0.f, 0.f);
    #pragma unroll
    for (int ks = 0; ks < G2_KS; ++ks) {
        float4 v = *(const float4*)(P + (size_t)ks * ROWS * XDIM + (size_t)i * 4);
        acc.x += v.x; acc.y += v.y; acc.z += v.z; acc.w += v.w;
    }
    *(float4*)(XDBLo + (size_t)i * 4) = acc;
    if (dtbf) {
        int row = (i * 4) / XDIM;
        int col = (i * 4) - row * XDIM;
        if (col < DT_RANK) {
            ushort4 o; o.x = f2bf(acc.x); o.y = f2bf(acc.y); o.z = f2bf(acc.z); o.w = f2bf(acc.w);
            *reinterpret_cast<ushort4*>(dtbf + (size_t)row * DT_RANK + col) = o;
        }
    }
}

// ---------------- generic fp32 NT GEMM (fallback path C) ----------------
#define BM 64
#define BN 64
#define BK 16
__global__ __launch_bounds__(256) void gemm_nt(const float* __restrict__ A, int lda,
                                               const float* __restrict__ B, int ldb,
                                               float* __restrict__ C, int ldc,
                                               int M, int N, int K,
                                               const float* __restrict__ bias, int epilogue)
{
    __shared__ float As[BM][BK + 1];
    __shared__ float Bs[BN][BK + 1];
    int t  = threadIdx.x;
    int m0 = blockIdx.y * BM;
    int n0 = blockIdx.x * BN;
    int lrow = t >> 2;
    int lk   = (t & 3) * 4;
    int tm   = t >> 4;
    int tn   = t & 15;

    float acc[4][4];
    #pragma unroll
    for (int i = 0; i < 4; ++i)
        #pragma unroll
        for (int j = 0; j < 4; ++j) acc[i][j] = 0.f;

    for (int k0 = 0; k0 < K; k0 += BK) {
        {
            int row = m0 + lrow;
            float4 v = make_float4(0.f, 0.f, 0.f, 0.f);
            if (row < M) v = *reinterpret_cast<const float4*>(A + (size_t)row * lda + k0 + lk);
            As[lrow][lk + 0] = v.x; As[lrow][lk + 1] = v.y;
            As[lrow][lk + 2] = v.z; As[lrow][lk + 3] = v.w;
        }
        {
            int row = n0 + lrow;
            float4 v = make_float4(0.f, 0.f, 0.f, 0.f);
            if (row < N) v = *reinterpret_cast<const float4*>(B + (size_t)row * ldb + k0 + lk);
            Bs[lrow][lk + 0] = v.x; Bs[lrow][lk + 1] = v.y;
            Bs[lrow][lk + 2] = v.z; Bs[lrow][lk + 3] = v.w;
        }
        __syncthreads();
        #pragma unroll
        for (int kk = 0; kk < BK; ++kk) {
            float a[4], b[4];
            #pragma unroll
            for (int i = 0; i < 4; ++i) a[i] = As[tm * 4 + i][kk];
            #pragma unroll
            for (int j = 0; j < 4; ++j) b[j] = Bs[tn * 4 + j][kk];
            #pragma unroll
            for (int i = 0; i < 4; ++i)
                #pragma unroll
                for (int j = 0; j < 4; ++j) acc[i][j] += a[i] * b[j];
        }
        __syncthreads();
    }

    #pragma unroll
    for (int i = 0; i < 4; ++i) {
        int m = m0 + tm * 4 + i;
        if (m >= M) continue;
        #pragma unroll
        for (int j = 0; j < 4; ++j) {
            int n = n0 + tn * 4 + j;
            if (n >= N) continue;
            float v = acc[i][j];
            if (epilogue == 1) {
                v += bias[n];
                v = fmaxf(v, 0.f) + log1pf(__expf(-fabsf(v)));
            }
            C[(size_t)m * ldc + n] = v;
        }
    }
}

// ---------------- conv+silu, f32 (paths B/C) ----------------
__global__ __launch_bounds__(256) void conv_silu_kernel(const float* __restrict__ XZ,
    const float* __restrict__ cw, const float* __restrict__ cb, float* __restrict__ XC)
{
    int idx = blockIdx.x * 256 + threadIdx.x;
    if (idx >= ROWS * (D_INNER / 4)) return;
    int d4   = idx % (D_INNER / 4);
    int rl   = idx / (D_INNER / 4);
    int l    = rl & (SEQ - 1);
    int base = rl - l;
    int d    = d4 * 4;

    float4 acc = reinterpret_cast<const float4*>(cb)[d4];
    float w[4][4];
    #pragma unroll
    for (int dd = 0; dd < 4; ++dd) {
        float4 wv = *reinterpret_cast<const float4*>(cw + (size_t)(d + dd) * 4);
        w[dd][0] = wv.x; w[dd][1] = wv.y; w[dd][2] = wv.z; w[dd][3] = wv.w;
    }
    #pragma unroll
    for (int k = 0; k < 4; ++k) {
        int lr = l - 3 + k;
        if (lr < 0) continue;
        float4 u = *reinterpret_cast<const float4*>(XZ + (size_t)(base + lr) * XZLD + d);
        acc.x += w[0][k] * u.x; acc.y += w[1][k] * u.y;
        acc.z += w[2][k] * u.z; acc.w += w[3][k] * u.w;
    }
    acc.x = acc.x / (1.f + __expf(-acc.x));
    acc.y = acc.y / (1.f + __expf(-acc.y));
    acc.z = acc.z / (1.f + __expf(-acc.z));
    acc.w = acc.w / (1.f + __expf(-acc.w));
    reinterpret_cast<float4*>(XC)[idx] = acc;
}

// ================= chunked scan, thread-per-channel (CL=32/NC=32) =================
// Fast path: when a[s] == -(s+1) (runtime-verified), exp(dl*a[s]) = exp(-dl)^(s+1).

// path A phase 1: delta bf16 dense (DL), u bf16 dense (XCbf)
__global__ __launch_bounds__(SDB) void scan_part1b(const unsigned short* __restrict__ XCbf,
    const unsigned short* __restrict__ DL, const float* __restrict__ XDBL,
    const float* __restrict__ A_log, float* __restrict__ Psum, float* __restrict__ Ssum)
{
    __shared__ float sB[CL][16];
    int tid = threadIdx.x;
    int d = blockIdx.x * SDB + tid;
    int c = blockIdx.y, b = blockIdx.z;
    size_t r0 = (size_t)b * SEQ + (size_t)c * CL;

    if (tid < CL * 4) {
        int t = tid >> 2, j = (tid & 3) * 4;
        *(float4*)&sB[t][j] = *(const float4*)(XDBL + (r0 + t) * XDIM + DT_RANK + j);
    }

    float a[D_STATE], S[D_STATE];
    #pragma unroll
    for (int i = 0; i < 4; ++i) {
        float4 v = *(const float4*)(A_log + (size_t)d * D_STATE + i * 4);
        a[i*4+0] = -__expf(v.x); a[i*4+1] = -__expf(v.y);
        a[i*4+2] = -__expf(v.z); a[i*4+3] = -__expf(v.w);
    }
    bool powok = true;
    #pragma unroll
    for (int s = 0; s < D_STATE; ++s)
        powok = powok && (fabsf(a[s] + (float)(s + 1)) < 1e-3f * (float)(s + 1));
    #pragma unroll
    for (int s = 0; s < D_STATE; ++s) S[s] = 0.f;
    float sumdl = 0.f;
    __syncthreads();

    if (powok) {
        for (int t = 0; t < CL; ++t) {
            float dl = bf2f(DL[(r0 + t) * D_INNER + d]);
            float uu = bf2f(XCbf[(r0 + t) * D_INNER + d]);
            float du = dl * uu;
            sumdl += dl;
            float4 b0 = *(const float4*)&sB[t][0];
            float4 b1 = *(const float4*)&sB[t][4];
            float4 b2 = *(const float4*)&sB[t][8];
            float4 b3 = *(const float4*)&sB[t][12];
            float bv[16] = {b0.x,b0.y,b0.z,b0.w, b1.x,b1.y,b1.z,b1.w,
                            b2.x,b2.y,b2.z,b2.w, b3.x,b3.y,b3.z,b3.w};
            float e1 = __expf(-dl);
            float E[16];
            POW_TREE(E, e1)
            #pragma unroll
            for (int s = 0; s < D_STATE; ++s)
                S[s] = E[s] * S[s] + du * bv[s];
        }
    } else {
        for (int t = 0; t < CL; ++t) {
            float dl = bf2f(DL[(r0 + t) * D_INNER + d]);
            float uu = bf2f(XCbf[(r0 + t) * D_INNER + d]);
            float du = dl * uu;
            sumdl += dl;
            float4 b0 = *(const float4*)&sB[t][0];
            float4 b1 = *(const float4*)&sB[t][4];
            float4 b2 = *(const float4*)&sB[t][8];
            float4 b3 = *(const float4*)&sB[t][12];
            float bv[16] = {b0.x,b0.y,b0.z,b0.w, b1.x,b1.y,b1.z,b1.w,
                            b2.x,b2.y,b2.z,b2.w, b3.x,b3.y,b3.z,b3.w};
            #pragma unroll
            for (int s = 0; s < D_STATE; ++s) {
                float e = __expf(dl * a[s]);
                S[s] = e * S[s] + du * bv[s];
            }
        }
    }

    size_t o = (((size_t)b * NC + c) * D_INNER + d) * D_STATE;
    #pragma unroll
    for (int i = 0; i < 4; ++i) {
        float4 p, s4;
        p.x = __expf(a[i*4+0] * sumdl); p.y = __expf(a[i*4+1] * sumdl);
        p.z = __expf(a[i*4+2] * sumdl); p.w = __expf(a[i*4+3] * sumdl);
        s4.x = S[i*4+0]; s4.y = S[i*4+1]; s4.z = S[i*4+2]; s4.w = S[i*4+3];
        *(float4*)(Psum + o + i * 4) = p;
        *(float4*)(Ssum + o + i * 4) = s4;
    }
}

// chunk-level prefix, in place
__global__ __launch_bounds__(256) void scan_prefix(float* __restrict__ Psum,
    const float* __restrict__ Ssum)
{
    int idx = blockIdx.x * 256 + threadIdx.x;
    int b = idx >> 15;
    int rem = idx & 32767;
    float h = 0.f;
    for (int c = 0; c < NC; ++c) {
        size_t o = (((size_t)b * NC + c) * D_INNER * D_STATE) + rem;
        float p = Psum[o];
        float s = Ssum[o];
        Psum[o] = h;
        h = p * h + s;
    }
}

// path A phase 2: out bf16 in place (DL) -> GEMM4 A
__global__ __launch_bounds__(SDB) void scan_part2b(const unsigned short* __restrict__ XCbf,
    unsigned short* __restrict__ DL, const unsigned short* __restrict__ XZbf,
    const float* __restrict__ XDBL, const float* __restrict__ A_log,
    const float* __restrict__ Dp, const float* __restrict__ Hin)
{
    __shared__ float sBC[CL][32];
    int tid = threadIdx.x;
    int d = blockIdx.x * SDB + tid;
    int c = blockIdx.y, b = blockIdx.z;
    size_t r0 = (size_t)b * SEQ + (size_t)c * CL;

    {
        int t = tid >> 3, j = (tid & 7) * 4;
        *(float4*)&sBC[t][j] = *(const float4*)(XDBL + (r0 + t) * XDIM + DT_RANK + j);
    }

    float a[D_STATE], h[D_STATE];
    #pragma unroll
    for (int i = 0; i < 4; ++i) {
        float4 v = *(const float4*)(A_log + (size_t)d * D_STATE + i * 4);
        a[i*4+0] = -__expf(v.x); a[i*4+1] = -__expf(v.y);
        a[i*4+2] = -__expf(v.z); a[i*4+3] = -__expf(v.w);
    }
    bool powok = true;
    #pragma unroll
    for (int s = 0; s < D_STATE; ++s)
        powok = powok && (fabsf(a[s] + (float)(s + 1)) < 1e-3f * (float)(s + 1));
    size_t ho = (((size_t)b * NC + c) * D_INNER + d) * D_STATE;
    #pragma unroll
    for (int i = 0; i < 4; ++i) {
        float4 v = *(const float4*)(Hin + ho + i * 4);
        h[i*4+0] = v.x; h[i*4+1] = v.y; h[i*4+2] = v.z; h[i*4+3] = v.w;
    }
    float dp = Dp[d];
    __syncthreads();

    if (powok) {
        for (int t = 0; t < CL; ++t) {
            float dl = bf2f(DL[(r0 + t) * D_INNER + d]);
            float uu = bf2f(XCbf[(r0 + t) * D_INNER + d]);
            float z  = bf2f(XZbf[(r0 + t) * XZLD + D_INNER + d]);
            float du = dl * uu;
            float4 b0 = *(const float4*)&sBC[t][0];
            float4 b1 = *(const float4*)&sBC[t][4];
            float4 b2 = *(const float4*)&sBC[t][8];
            float4 b3 = *(const float4*)&sBC[t][12];
            float4 c0 = *(const float4*)&sBC[t][16];
            float4 c1 = *(const float4*)&sBC[t][20];
            float4 c2 = *(const float4*)&sBC[t][24];
            float4 c3 = *(const float4*)&sBC[t][28];
            float bv[16] = {b0.x,b0.y,b0.z,b0.w, b1.x,b1.y,b1.z,b1.w,
                            b2.x,b2.y,b2.z,b2.w, b3.x,b3.y,b3.z,b3.w};
            float cv[16] = {c0.x,c0.y,c0.z,c0.w, c1.x,c1.y,c1.z,c1.w,
                            c2.x,c2.y,c2.z,c2.w, c3.x,c3.y,c3.z,c3.w};
            float e1 = __expf(-dl);
            float E[16];
            POW_TREE(E, e1)
            float y = 0.f;
            #pragma unroll
            for (int s = 0; s < D_STATE; ++s) {
                h[s] = E[s] * h[s] + du * bv[s];
                y += h[s] * cv[s];
            }
            float sz = z / (1.f + __expf(-z));
            DL[(r0 + t) * D_INNER + d] = f2bf((y + uu * dp) * sz);
        }
    } else {
        for (int t = 0; t < CL; ++t) {
            float dl = bf2f(DL[(r0 + t) * D_INNER + d]);
            float uu = bf2f(XCbf[(r0 + t) * D_INNER + d]);
            float z  = bf2f(XZbf[(r0 + t) * XZLD + D_INNER + d]);
            float du = dl * uu;
            float4 b0 = *(const float4*)&sBC[t][0];
            float4 b1 = *(const float4*)&sBC[t][4];
            float4 b2 = *(const float4*)&sBC[t][8];
            float4 b3 = *(const float4*)&sBC[t][12];
            float4 c0 = *(const float4*)&sBC[t][16];
            float4 c1 = *(const float4*)&sBC[t][20];
            float4 c2 = *(const float4*)&sBC[t][24];
            float4 c3 = *(const float4*)&sBC[t][28];
            float bv[16] = {b0.x,b0.y,b0.z,b0.w, b1.x,b1.y,b1.z,b1.w,
                            b2.x,b2.y,b2.z,b2.w, b3.x,b3.y,b3.z,b3.w};
            float cv[16] = {c0.x,c0.y,c0.z,c0.w, c1.x,c1.y,c1.z,c1.w,
                            c2.x,c2.y,c2.z,c2.w, c3.x,c3.y,c3.z,c3.w};
            float y = 0.f;
            #pragma unroll
            for (int s = 0; s < D_STATE; ++s) {
                float e = __expf(dl * a[s]);
                h[s] = e * h[s] + du * bv[s];
                y += h[s] * cv[s];
            }
            float sz = z / (1.f + __expf(-z));
            DL[(r0 + t) * D_INNER + d] = f2bf((y + uu * dp) * sz);
        }
    }
}

// ---- path B scan variants (f32) ----
__global__ __launch_bounds__(SDB) void scan_part1(const float* __restrict__ XC,
    const float* __restrict__ XZ, const float* __restrict__ XDBL,
    const float* __restrict__ A_log, float* __restrict__ Psum, float* __restrict__ Ssum)
{
    __shared__ float sB[CL][16];
    int tid = threadIdx.x;
    int d = blockIdx.x * SDB + tid;
    int c = blockIdx.y, b = blockIdx.z;
    size_t r0 = (size_t)b * SEQ + (size_t)c * CL;

    if (tid < CL * 4) {
        int t = tid >> 2, j = (tid & 3) * 4;
        *(float4*)&sB[t][j] = *(const float4*)(XDBL + (r0 + t) * XDIM + DT_RANK + j);
    }

    float a[D_STATE], S[D_STATE];
    #pragma unroll
    for (int i = 0; i < 4; ++i) {
        float4 v = *(const float4*)(A_log + (size_t)d * D_STATE + i * 4);
        a[i*4+0] = -__expf(v.x); a[i*4+1] = -__expf(v.y);
        a[i*4+2] = -__expf(v.z); a[i*4+3] = -__expf(v.w);
    }
    #pragma unroll
    for (int s = 0; s < D_STATE; ++s) S[s] = 0.f;
    float sumdl = 0.f;
    __syncthreads();

    for (int t = 0; t < CL; ++t) {
        float dl = XZ[(r0 + t) * XZLD + d];
        float uu = XC[(r0 + t) * D_INNER + d];
        float du = dl * uu;
        sumdl += dl;
        float4 b0 = *(const float4*)&sB[t][0];
        float4 b1 = *(const float4*)&sB[t][4];
        float4 b2 = *(const float4*)&sB[t][8];
        float4 b3 = *(const float4*)&sB[t][12];
        float bv[16] = {b0.x,b0.y,b0.z,b0.w, b1.x,b1.y,b1.z,b1.w,
                        b2.x,b2.y,b2.z,b2.w, b3.x,b3.y,b3.z,b3.w};
        #pragma unroll
        for (int s = 0; s < D_STATE; ++s) {
            float e = __expf(dl * a[s]);
            S[s] = e * S[s] + du * bv[s];
        }
    }

    size_t o = (((size_t)b * NC + c) * D_INNER + d) * D_STATE;
    #pragma unroll
    for (int i = 0; i < 4; ++i) {
        float4 p, s4;
        p.x = __expf(a[i*4+0] * sumdl); p.y = __expf(a[i*4+1] * sumdl);
        p.z = __expf(a[i*4+2] * sumdl); p.w = __expf(a[i*4+3] * sumdl);
        s4.x = S[i*4+0]; s4.y = S[i*4+1]; s4.z = S[i*4+2]; s4.w = S[i*4+3];
        *(float4*)(Psum + o + i * 4) = p;
        *(float4*)(Ssum + o + i * 4) = s4;
    }
}

__global__ __launch_bounds__(SDB) void scan_part2(const float* __restrict__ XC,
    float* __restrict__ XZ, const float* __restrict__ XDBL,
    const float* __restrict__ A_log, const float* __restrict__ Dp,
    const float* __restrict__ Hin)
{
    __shared__ float sBC[CL][32];
    int tid = threadIdx.x;
    int d = blockIdx.x * SDB + tid;
    int c = blockIdx.y, b = blockIdx.z;
    size_t r0 = (size_t)b * SEQ + (size_t)c * CL;

    {
        int t = tid >> 3, j = (tid & 7) * 4;
        *(float4*)&sBC[t][j] = *(const float4*)(XDBL + (r0 + t) * XDIM + DT_RANK + j);
    }

    float a[D_STATE], h[D_STATE];
    #pragma unroll
    for (int i = 0; i < 4; ++i) {
        float4 v = *(const float4*)(A_log + (size_t)d * D_STATE + i * 4);
        a[i*4+0] = -__expf(v.x); a[i*4+1] = -__expf(v.y);
        a[i*4+2] = -__expf(v.z); a[i*4+3] = -__expf(v.w);
    }
    size_t ho = (((size_t)b * NC + c) * D_INNER + d) * D_STATE;
    #pragma unroll
    for (int i = 0; i < 4; ++i) {
        float4 v = *(const float4*)(Hin + ho + i * 4);
        h[i*4+0] = v.x; h[i*4+1] = v.y; h[i*4+2] = v.z; h[i*4+3] = v.w;
    }
    float dp = Dp[d];
    __syncthreads();

    for (int t = 0; t < CL; ++t) {
        float dl = XZ[(r0 + t) * XZLD + d];
        float uu = XC[(r0 + t) * D_INNER + d];
        float z  = XZ[(r0 + t) * XZLD + D_INNER + d];
        float du = dl * uu;
        float4 b0 = *(const float4*)&sBC[t][0];
        float4 b1 = *(const float4*)&sBC[t][4];
        float4 b2 = *(const float4*)&sBC[t][8];
        float4 b3 = *(const float4*)&sBC[t][12];
        float4 c0 = *(const float4*)&sBC[t][16];
        float4 c1 = *(const float4*)&sBC[t][20];
        float4 c2 = *(const float4*)&sBC[t][24];
        float4 c3 = *(const float4*)&sBC[t][28];
        float bv[16] = {b0.x,b0.y,b0.z,b0.w, b1.x,b1.y,b1.z,b1.w,
                        b2.x,b2.y,b2.z,b2.w, b3.x,b3.y,b3.z,b3.w};
        float cv[16] = {c0.x,c0.y,c0.z,c0.w, c1.x,c1.y,c1.z,c1.w,
                        c2.x,c2.y,c2.z,c2.w, c3.x,c3.y,c3.z,c3.w};
        float y = 0.f;
        #pragma unroll
        for (int s = 0; s < D_STATE; ++s) {
            float e = __expf(dl * a[s]);
            h[s] = e * h[s] + du * bv[s];
            y += h[s] * cv[s];
        }
        float sz = z / (1.f + __expf(-z));
        XZ[(r0 + t) * XZLD + d] = (y + uu * dp) * sz;
    }
}

// ---------------- fallback sequential scan (path C) ----------------
__global__ __launch_bounds__(256) void scan_kernel2(const float* __restrict__ XC,
    float* __restrict__ XZ, const float* __restrict__ XDBL,
    const float* __restrict__ A_log, const float* __restrict__ Dp)
{
    int tid = threadIdx.x;
    int s  = tid & 15;
    int dd = tid >> 4;
    int d  = blockIdx.x * 16 + dd;
    int b  = blockIdx.y;

    float a  = -__expf(A_log[(size_t)d * D_STATE + s]);
    float h  = 0.f;
    float dp = Dp[d];
    const size_t rbase = (size_t)b * SEQ;

    for (int t = 0; t < SEQ; ++t) {
        size_t r = rbase + t;
        float dl = XZ[r * XZLD + d];
        float uu = XC[r * D_INNER + d];
        float z  = XZ[r * XZLD + D_INNER + d];
        float Bv = XDBL[r * XDIM + DT_RANK + s];
        float Cv = XDBL[r * XDIM + DT_RANK + D_STATE + s];
        float e  = __expf(dl * a);
        h = e * h + dl * uu * Bv;
        float y = h * Cv;
        y += __shfl_xor(y, 1);
        y += __shfl_xor(y, 2);
        y += __shfl_xor(y, 4);
        y += __shfl_xor(y, 8);
        if (s == 0) {
            float sz = z / (1.f + __expf(-z));
            XZ[r * XZLD + d] = (y + uu * dp) * sz;
        }
    }
}

extern "C" void kernel_launch(void* const* d_in, const int* in_sizes, int n_in,
                              void* d_out, int out_size, void* d_ws, size_t ws_size,
                              hipStream_t stream)
{
    const float* pe    = (const float*)d_in[0];
    const float* cond  = (const float*)d_in[1];
    const float* W_in  = (const float*)d_in[2];
    const float* cw    = (const float*)d_in[3];
    const float* cb    = (const float*)d_in[4];
    const float* W_x   = (const float*)d_in[5];
    const float* W_dt  = (const float*)d_in[6];
    const float* b_dt  = (const float*)d_in[7];
    const float* A_log = (const float*)d_in[8];
    const float* Dp    = (const float*)d_in[9];
    const float* W_out = (const float*)d_in[10];

    float* X = (float*)d_out;                          // [2048,1024] final output only

    // ---------------- path A layout (~86 MB) ----------------
    char* wsp = (char*)d_ws;
    unsigned short* XZbf = (unsigned short*)wsp;                       // [2048][4096] 16.8MB
    unsigned short* XCbf = (unsigned short*)(wsp + 16777216);          // [2048][2048] bf16 8.4MB
    unsigned short* XOUT = XCbf;                                       // l0 GEMM4 out [2048][1024] (same slot, serial lifetimes)
    float* XDBL  = (float*)(wsp + 33554432);                           // [2048][96]   0.8MB
    unsigned short* BF0   = (unsigned short*)(wsp + 34340864);         // [2048][2048] 8.4MB (x/delta/out)
    unsigned short* dtbf  = (unsigned short*)(wsp + 42729472);         // [2048][64]   0.26MB
    unsigned short* WINbf = (unsigned short*)(wsp + 42991616);         // 2x[4096][1024] 16.8MB
    unsigned short* WOUTbf= (unsigned short*)(wsp + 59768832);         // 2x[1024][2048] 8.4MB
    unsigned short* WDTbf = (unsigned short*)(wsp + 68157440);         // 2x[2048][64]  0.52MB
    float* SCR   = (float*)(wsp + 68681728);                           // 16.8MB scratch
    size_t need_A = 68681728 + 16777216;                               // ~85.5MB

    // ---------------- path B layout (round-6, ~68MB) ----------------
    float* XZb   = (float*)d_ws;
    float* XCb   = XZb + (size_t)ROWS * XZLD;
    float* XDBLb = XCb + (size_t)ROWS * D_INNER;
    void* rest = (void*)(XDBLb + (size_t)ROWS * XDIM);
    unsigned short* Abf = (unsigned short*)rest;
    unsigned short* Bbf = Abf + (size_t)ROWS * D_INNER;
    float* PpartB = (float*)rest;
    float* PsumB  = (float*)rest;
    float* SsumB  = PsumB + (size_t)BATCH * NC * D_INNER * D_STATE;
    size_t need_B = ((size_t)ROWS * XZLD + (size_t)ROWS * D_INNER + (size_t)ROWS * XDIM) * 4
                  + ((size_t)ROWS * D_INNER + (size_t)ROWS * D_INNER) * 2;

    if (ws_size >= need_A) {
        // =========================== PATH A ===========================
        float* Psum = SCR;                                             // 8.4MB (NC=32)
        float* Ssum = SCR + (size_t)BATCH * NC * D_INNER * D_STATE;    // 8.4MB

        // one-time: all weights + x -> bf16 in ONE dispatch
        conv_wall<<<(WN1 + WN2 + WN3 + WN4 + 255) / 256, 256, 0, stream>>>(
            W_in, W_out, W_dt, pe, cond, WINbf, WOUTbf, WDTbf, BF0);

        for (int l = 0; l < NLAYERS; ++l) {
            const unsigned short* WINl  = WINbf  + (size_t)l * 2 * D_INNER * D_MODEL;
            const unsigned short* WOUTl = WOUTbf + (size_t)l * D_MODEL * D_INNER;
            const unsigned short* WDTl  = WDTbf  + (size_t)l * D_INNER * DT_RANK;
            const float* W_x_l   = W_x   + (size_t)l * XDIM * D_INNER;
            const float* cw_l    = cw    + (size_t)l * D_INNER * 4;
            const float* cb_l    = cb    + (size_t)l * D_INNER;
            const float* b_dt_l  = b_dt  + (size_t)l * D_INNER;
            const float* A_log_l = A_log + (size_t)l * D_INNER * D_STATE;
            const float* Dp_l    = Dp    + (size_t)l * D_INNER;
            const unsigned short* xin = (l == 0) ? BF0 : XOUT;   // layer input x (bf16)

            // GEMM1: xz(bf16) = x(bf16) @ W_in^T
            gemm_bf16_nt_bfout<<<dim3(2 * D_INNER / GBN, ROWS / GBM), 256, 0, stream>>>(
                xin, WINl, XZbf, ROWS, 2 * D_INNER, D_MODEL, XZLD);
            // FUSED conv+silu + GEMM2 split-K (xc -> XCbf bf16, partials -> SCR)
            gemm2_fused<<<dim3(ROWS / G2_ROWS, G2_KS), 256, 0, stream>>>(
                XZbf, cw_l, cb_l, W_x_l, XCbf, SCR);
            gemm2_reduce<<<(ROWS * XDIM / 4 + 255) / 256, 256, 0, stream>>>(SCR, XDBL, dtbf);
            // GEMM3: delta(bf16 dense) = softplus(dt @ W_dt^T + b_dt) -> BF0
            gemm_bf16_sp_bfout<<<dim3(D_INNER / GBN, ROWS / GBM), 256, 0, stream>>>(
                dtbf, WDTl, BF0, ROWS, D_INNER, DT_RANK, D_INNER, b_dt_l);
            // chunked scan (out bf16 in place -> GEMM4 A)
            scan_part1b<<<dim3(D_INNER / SDB, NC, BATCH), SDB, 0, stream>>>(
                XCbf, BF0, XDBL, A_log_l, Psum, Ssum);
            scan_prefix<<<BATCH * D_INNER * D_STATE / 256, 256, 0, stream>>>(Psum, Ssum);
            scan_part2b<<<dim3(D_INNER / SDB, NC, BATCH), SDB, 0, stream>>>(
                XCbf, BF0, XZbf, XDBL, A_log_l, Dp_l, Psum);
            // GEMM4: x = out @ W_out^T, 128x64 tile, no split-K
            //   l0 -> bf16 XOUT (next-layer GEMM1 A);  l1 -> f32 X (d_out)
            gemm_bf16_nt64<<<dim3(D_MODEL / G4BN, ROWS / GBM), 256, 0, stream>>>(
                BF0, D_INNER, WOUTl, D_INNER,
                (l < NLAYERS - 1) ? XOUT : nullptr,
                (l == NLAYERS - 1) ? X : nullptr,
                ROWS, D_MODEL, D_INNER);
        }
    } else if (ws_size >= need_B) {
        // =========================== PATH B (round-6) ===========================
        add_pe_kernel<<<ROWS * D_MODEL / 4 / 256, 256, 0, stream>>>(pe, cond, X);
        for (int l = 0; l < NLAYERS; ++l) {
            const float* W_in_l  = W_in  + (size_t)l * 2 * D_INNER * D_MODEL;
            const float* W_out_l = W_out + (size_t)l * D_MODEL * D_INNER;
            const float* W_x_l   = W_x   + (size_t)l * XDIM * D_INNER;
            const float* W_dt_l  = W_dt  + (size_t)l * D_INNER * DT_RANK;
            const float* b_dt_l  = b_dt  + (size_t)l * D_INNER;
            const float* A_log_l = A_log + (size_t)l * D_INNER * D_STATE;
            const float* Dp_l    = Dp    + (size_t)l * D_INNER;

            conv_bf16_dense<<<(ROWS * D_MODEL / 4 + 255) / 256, 256, 0, stream>>>(X, Abf, ROWS * D_MODEL / 4);
            conv_bf16_dense<<<(2 * D_INNER * D_MODEL / 4 + 255) / 256, 256, 0, stream>>>(W_in_l, Bbf, 2 * D_INNER * D_MODEL / 4);
            gemm_bf16_nt<<<dim3(2 * D_INNER / GBN, ROWS / GBM), 256, 0, stream>>>(
                Abf, Bbf, XZb, ROWS, 2 * D_INNER, D_MODEL, XZLD, nullptr, 0);
            conv_silu_kernel<<<ROWS * (D_INNER / 4) / 256, 256, 0, stream>>>(
                XZb, cw + (size_t)l * D_INNER * 4, cb + (size_t)l * D_INNER, XCb);
            gemm2_splitk<<<dim3(ROWS / G2_ROWS, G2_KS), 256, 0, stream>>>(XCb, W_x_l, PpartB);
            gemm2_reduce<<<(ROWS * XDIM / 4 + 255) / 256, 256, 0, stream>>>(PpartB, XDBLb, nullptr);
            conv_bf16_dtcols<<<(ROWS * DT_RANK / 4 + 255) / 256, 256, 0, stream>>>(XDBLb, Abf);
            conv_bf16_dense<<<(D_INNER * DT_RANK / 4 + 255) / 256, 256, 0, stream>>>(W_dt_l, Bbf, D_INNER * DT_RANK / 4);
            gemm_bf16_nt<<<dim3(D_INNER / GBN, ROWS / GBM), 256, 0, stream>>>(
                Abf, Bbf, XZb, ROWS, D_INNER, DT_RANK, XZLD, b_dt_l, 1);
            scan_part1<<<dim3(D_INNER / SDB, NC, BATCH), SDB, 0, stream>>>(
                XCb, XZb, XDBLb, A_log_l, PsumB, SsumB);
            scan_prefix<<<BATCH * D_INNER * D_STATE / 256, 256, 0, stream>>>(PsumB, SsumB);
            scan_part2<<<dim3(D_INNER / SDB, NC, BATCH), SDB, 0, stream>>>(
                XCb, XZb, XDBLb, A_log_l, Dp_l, PsumB);
            conv_bf16_strided<<<(ROWS * D_INNER / 4 + 255) / 256, 256, 0, stream>>>(
                XZb, XZLD, D_INNER, Abf, ROWS * D_INNER / 4);
            conv_bf16_dense<<<(D_MODEL * D_INNER / 4 + 255) / 256, 256, 0, stream>>>(W_out_l, Bbf, D_MODEL * D_INNER / 4);
            gemm_bf16_nt<<<dim3(D_MODEL / GBN, ROWS / GBM), 256, 0, stream>>>(
                Abf, Bbf, X, ROWS, D_MODEL, D_INNER, D_MODEL, nullptr, 0);
        }
    } else {
        // =========================== PATH C (fp32) ===========================
        add_pe_kernel<<<ROWS * D_MODEL / 4 / 256, 256, 0, stream>>>(pe, cond, X);
        for (int l = 0; l < NLAYERS; ++l) {
            gemm_nt<<<dim3(2 * D_INNER / BN, ROWS / BM), 256, 0, stream>>>(
                X, D_MODEL, W_in + (size_t)l * 2 * D_INNER * D_MODEL, D_MODEL,
                XZb, XZLD, ROWS, 2 * D_INNER, D_MODEL, nullptr, 0);
            conv_silu_kernel<<<ROWS * (D_INNER / 4) / 256, 256, 0, stream>>>(
                XZb, cw + (size_t)l * D_INNER * 4, cb + (size_t)l * D_INNER, XCb);
            gemm_nt<<<dim3((XDIM + BN - 1) / BN, ROWS / BM), 256, 0, stream>>>(
                XCb, D_INNER, W_x + (size_t)l * XDIM * D_INNER, D_INNER,
                XDBLb, XDIM, ROWS, XDIM, D_INNER, nullptr, 0);
            gemm_nt<<<dim3(D_INNER / BN, ROWS / BM), 256, 0, stream>>>(
                XDBLb, XDIM, W_dt + (size_t)l * D_INNER * DT_RANK, DT_RANK,
                XZb, XZLD, ROWS, D_INNER, DT_RANK, b_dt + (size_t)l * D_INNER, 1);
            scan_kernel2<<<dim3(D_INNER / 16, BATCH), 256, 0, stream>>>(
                XCb, XZb, XDBLb, A_log + (size_t)l * D_INNER * D_STATE, Dp + (size_t)l * D_INNER);
            gemm_nt<<<dim3(D_MODEL / BN, ROWS / BM), 256, 0, stream>>>(
                XZb, XZLD, W_out + (size_t)l * D_MODEL * D_INNER, D_INNER,
                X, D_MODEL, ROWS, D_MODEL, D_INNER, nullptr, 0);
        }
    }
}

// Round 15
// 320.810 us; speedup vs baseline: 1.1269x; 1.0204x over previous
//
#include <hip/hip_runtime.h>
#include <math.h>

#define D_MODEL 1024
#define D_INNER 2048
#define D_STATE 16
#define DT_RANK 64
#define SEQ 1024
#define BATCH 2
#define NLAYERS 2
#define ROWS (BATCH*SEQ)      // 2048
#define XDIM 96               // dt_rank + 2*d_state
#define XZLD (2*D_INNER)      // 4096

// chunked scan geometry — CL=32/NC=32 measured-best
#define NC 32
#define CL 32
#define SDB 256

// GEMM2 split-K geometry
#define G2_ROWS 64
#define G2_KC 128
#define G2_BK 32
#define G2_KS (D_INNER / G2_KC)

typedef short bf16x8 __attribute__((ext_vector_type(8)));
typedef float f32x4  __attribute__((ext_vector_type(4)));

// ---------------- helpers ----------------
__device__ __forceinline__ unsigned short f2bf(float f) {
    union { float f; unsigned int u; } v; v.f = f;
    unsigned int u = v.u;
    return (unsigned short)((u + 0x7FFFu + ((u >> 16) & 1u)) >> 16);   // RNE
}
__device__ __forceinline__ float bf2f(unsigned short u) {
    union { unsigned int i; float f; } v; v.i = ((unsigned int)u) << 16; return v.f;
}

__device__ __forceinline__ void gload_lds16(const void* g, void* s) {
    __builtin_amdgcn_global_load_lds((const __attribute__((address_space(1))) void*)g,
                                     (__attribute__((address_space(3))) void*)s, 16, 0, 0);
}

// e1^(s+1) for s=0..15, depth-4 multiply tree
#define POW_TREE(E, e1)                                                         \
    E[0] = e1;          E[1] = e1 * e1;   E[2] = E[1] * e1;  E[3] = E[1] * E[1];\
    E[4] = E[3] * E[0]; E[5] = E[3] * E[1]; E[6] = E[3] * E[2]; E[7] = E[3] * E[3];\
    E[8] = E[7] * E[0]; E[9] = E[7] * E[1]; E[10] = E[7] * E[2]; E[11] = E[7] * E[3];\
    E[12] = E[7] * E[4]; E[13] = E[7] * E[5]; E[14] = E[7] * E[6]; E[15] = E[7] * E[7];

// ---------------- x = pe + condition (f32 out; paths B/C) ----------------
__global__ __launch_bounds__(256) void add_pe_kernel(const float* __restrict__ pe,
    const float* __restrict__ cond, float* __restrict__ X)
{
    int i = blockIdx.x * 256 + threadIdx.x;
    int total = ROWS * D_MODEL / 4;
    if (i >= total) return;
    int row  = i / (D_MODEL / 4);
    int l    = row & (SEQ - 1);
    int col4 = i - row * (D_MODEL / 4);
    float4 p = reinterpret_cast<const float4*>(pe)[l * (D_MODEL / 4) + col4];
    float4 c = reinterpret_cast<const float4*>(cond)[i];
    float4 r; r.x = p.x + c.x; r.y = p.y + c.y; r.z = p.z + c.z; r.w = p.w + c.w;
    reinterpret_cast<float4*>(X)[i] = r;
}

// ---------------- f32 -> bf16 conversions ----------------
__global__ __launch_bounds__(256) void conv_bf16_dense(const float* __restrict__ src,
    unsigned short* __restrict__ dst, int n4)
{
    int i = blockIdx.x * 256 + threadIdx.x;
    if (i >= n4) return;
    float4 v = reinterpret_cast<const float4*>(src)[i];
    ushort4 o; o.x = f2bf(v.x); o.y = f2bf(v.y); o.z = f2bf(v.z); o.w = f2bf(v.w);
    reinterpret_cast<ushort4*>(dst)[i] = o;
}

// one dispatch: all three weight tensors -> bf16 AND x = pe+cond -> bf16 (path A pre-loop)
#define WN1 (NLAYERS * 2 * D_INNER * D_MODEL / 4)
#define WN2 (NLAYERS * D_MODEL * D_INNER / 4)
#define WN3 (NLAYERS * D_INNER * DT_RANK / 4)
#define WN4 (ROWS * D_MODEL / 4)
__global__ __launch_bounds__(256) void conv_wall(const float* __restrict__ Win,
    const float* __restrict__ Wout, const float* __restrict__ Wdt,
    const float* __restrict__ pe, const float* __restrict__ cond,
    unsigned short* __restrict__ WINbf, unsigned short* __restrict__ WOUTbf,
    unsigned short* __restrict__ WDTbf, unsigned short* __restrict__ Xbf)
{
    int i = blockIdx.x * 256 + threadIdx.x;
    if (i < WN1) {
        float4 v = reinterpret_cast<const float4*>(Win)[i];
        ushort4 o; o.x = f2bf(v.x); o.y = f2bf(v.y); o.z = f2bf(v.z); o.w = f2bf(v.w);
        reinterpret_cast<ushort4*>(WINbf)[i] = o;
    } else if (i < WN1 + WN2) {
        int j = i - WN1;
        float4 v = reinterpret_cast<const float4*>(Wout)[j];
        ushort4 o; o.x = f2bf(v.x); o.y = f2bf(v.y); o.z = f2bf(v.z); o.w = f2bf(v.w);
        reinterpret_cast<ushort4*>(WOUTbf)[j] = o;
    } else if (i < WN1 + WN2 + WN3) {
        int j = i - WN1 - WN2;
        float4 v = reinterpret_cast<const float4*>(Wdt)[j];
        ushort4 o; o.x = f2bf(v.x); o.y = f2bf(v.y); o.z = f2bf(v.z); o.w = f2bf(v.w);
        reinterpret_cast<ushort4*>(WDTbf)[j] = o;
    } else if (i < WN1 + WN2 + WN3 + WN4) {
        int j = i - WN1 - WN2 - WN3;
        int row  = j / (D_MODEL / 4);
        int l    = row & (SEQ - 1);
        int col4 = j - row * (D_MODEL / 4);
        float4 p = reinterpret_cast<const float4*>(pe)[l * (D_MODEL / 4) + col4];
        float4 c = reinterpret_cast<const float4*>(cond)[j];
        ushort4 o;
        o.x = f2bf(p.x + c.x); o.y = f2bf(p.y + c.y);
        o.z = f2bf(p.z + c.z); o.w = f2bf(p.w + c.w);
        reinterpret_cast<ushort4*>(Xbf)[j] = o;
    }
}

__global__ __launch_bounds__(256) void conv_bf16_strided(const float* __restrict__ src,
    int ld, int cols, unsigned short* __restrict__ dst, int total4)
{
    int i = blockIdx.x * 256 + threadIdx.x;
    if (i >= total4) return;
    int c4  = cols / 4;
    int row = i / c4;
    int col = (i - row * c4) * 4;
    float4 v = *reinterpret_cast<const float4*>(src + (size_t)row * ld + col);
    ushort4 o; o.x = f2bf(v.x); o.y = f2bf(v.y); o.z = f2bf(v.z); o.w = f2bf(v.w);
    *reinterpret_cast<ushort4*>(dst + (size_t)row * cols + col) = o;
}

__global__ __launch_bounds__(256) void conv_bf16_dtcols(const float* __restrict__ XDBL,
    unsigned short* __restrict__ dst)
{
    int i = blockIdx.x * 256 + threadIdx.x;
    if (i >= ROWS * DT_RANK / 4) return;
    int m  = i >> 4;
    int c4 = (i & 15) * 4;
    float4 v = *reinterpret_cast<const float4*>(XDBL + (size_t)m * XDIM + c4);
    ushort4 o; o.x = f2bf(v.x); o.y = f2bf(v.y); o.z = f2bf(v.z); o.w = f2bf(v.w);
    *reinterpret_cast<ushort4*>(dst + (size_t)m * DT_RANK + c4) = o;
}

// ================= bf16 MFMA NT GEMM family =================
#define GBM 128
#define GBN 128
#define GBK 64

#define GEMM_STAGE(Ap, Bp, lda, ldb, koff)                                      \
    _Pragma("unroll")                                                           \
    for (int i_ = 0; i_ < 4; ++i_) {                                            \
        int off_ = w * 4096 + i_ * 1024 + l * 16;                               \
        int row_ = off_ >> 7;                                                   \
        int col_ = (off_ & 127) >> 1;                                           \
        gload_lds16(Ap + (size_t)(m0 + row_) * (lda) + (koff) + col_,           \
                    (char*)As + w * 4096 + i_ * 1024);                          \
    }                                                                           \
    _Pragma("unroll")                                                           \
    for (int i_ = 0; i_ < 4; ++i_) {                                            \
        int off_ = w * 4096 + i_ * 1024 + l * 16;                               \
        int row_ = off_ >> 7;                                                   \
        int col_ = (off_ & 127) >> 1;                                           \
        gload_lds16(Bp + (size_t)(n0 + row_) * (ldb) + (koff) + col_,           \
                    (char*)Bs + w * 4096 + i_ * 1024);                          \
    }

#define GEMM_MFMA_STEP                                                          \
    _Pragma("unroll")                                                           \
    for (int kk = 0; kk < 2; ++kk) {                                            \
        bf16x8 af[4], bfr[4];                                                   \
        _Pragma("unroll")                                                       \
        for (int m = 0; m < 4; ++m)                                             \
            af[m] = *(const bf16x8*)&As[(wr * 64 + m * 16 + fr) * GBK + kk * 32 + fq * 8]; \
        _Pragma("unroll")                                                       \
        for (int n = 0; n < 4; ++n)                                             \
            bfr[n] = *(const bf16x8*)&Bs[(wc * 64 + n * 16 + fr) * GBK + kk * 32 + fq * 8]; \
        _Pragma("unroll")                                                       \
        for (int m = 0; m < 4; ++m)                                             \
            _Pragma("unroll")                                                   \
            for (int n = 0; n < 4; ++n)                                         \
                acc[m][n] = __builtin_amdgcn_mfma_f32_16x16x32_bf16(af[m], bfr[n], acc[m][n], 0, 0, 0); \
    }

// f32 out, optional softplus epilogue (path B)
__global__ __launch_bounds__(256) void gemm_bf16_nt(const unsigned short* __restrict__ A,
    const unsigned short* __restrict__ B, float* __restrict__ C,
    int M, int N, int K, int ldc, const float* __restrict__ bias, int epilogue)
{
    __shared__ unsigned short As[GBM * GBK];
    __shared__ unsigned short Bs[GBN * GBK];
    int tid = threadIdx.x;
    int w = tid >> 6, l = tid & 63;
    int wr = w >> 1, wc = w & 1;
    int m0 = blockIdx.y * GBM, n0 = blockIdx.x * GBN;

    f32x4 acc[4][4];
    #pragma unroll
    for (int m = 0; m < 4; ++m)
        #pragma unroll
        for (int n = 0; n < 4; ++n) acc[m][n] = (f32x4){0.f, 0.f, 0.f, 0.f};
    int fr = l & 15, fq = l >> 4;

    for (int k0 = 0; k0 < K; k0 += GBK) {
        GEMM_STAGE(A, B, K, K, k0)
        __syncthreads();
        GEMM_MFMA_STEP
        __syncthreads();
    }

    #pragma unroll
    for (int m = 0; m < 4; ++m)
        #pragma unroll
        for (int n = 0; n < 4; ++n) {
            int col = n0 + wc * 64 + n * 16 + fr;
            #pragma unroll
            for (int j = 0; j < 4; ++j) {
                int row = m0 + wr * 64 + m * 16 + fq * 4 + j;
                float v = acc[m][n][j];
                if (epilogue == 1) {
                    v += bias[col];
                    v = fmaxf(v, 0.f) + log1pf(__expf(-fabsf(v)));
                }
                C[(size_t)row * ldc + col] = v;
            }
        }
}

// bf16 out, no epilogue (path A GEMM1)
__global__ __launch_bounds__(256) void gemm_bf16_nt_bfout(const unsigned short* __restrict__ A,
    const unsigned short* __restrict__ B, unsigned short* __restrict__ C,
    int M, int N, int K, int ldc)
{
    __shared__ unsigned short As[GBM * GBK];
    __shared__ unsigned short Bs[GBN * GBK];
    int tid = threadIdx.x;
    int w = tid >> 6, l = tid & 63;
    int wr = w >> 1, wc = w & 1;
    int m0 = blockIdx.y * GBM, n0 = blockIdx.x * GBN;

    f32x4 acc[4][4];
    #pragma unroll
    for (int m = 0; m < 4; ++m)
        #pragma unroll
        for (int n = 0; n < 4; ++n) acc[m][n] = (f32x4){0.f, 0.f, 0.f, 0.f};
    int fr = l & 15, fq = l >> 4;

    for (int k0 = 0; k0 < K; k0 += GBK) {
        GEMM_STAGE(A, B, K, K, k0)
        __syncthreads();
        GEMM_MFMA_STEP
        __syncthreads();
    }

    #pragma unroll
    for (int m = 0; m < 4; ++m)
        #pragma unroll
        for (int n = 0; n < 4; ++n) {
            int col = n0 + wc * 64 + n * 16 + fr;
            #pragma unroll
            for (int j = 0; j < 4; ++j) {
                int row = m0 + wr * 64 + m * 16 + fq * 4 + j;
                C[(size_t)row * ldc + col] = f2bf(acc[m][n][j]);
            }
        }
}

// softplus + bf16 out (GEMM3 path A)
__global__ __launch_bounds__(256) void gemm_bf16_sp_bfout(const unsigned short* __restrict__ A,
    const unsigned short* __restrict__ B, unsigned short* __restrict__ C,
    int M, int N, int K, int ldc, const float* __restrict__ bias)
{
    __shared__ unsigned short As[GBM * GBK];
    __shared__ unsigned short Bs[GBN * GBK];
    int tid = threadIdx.x;
    int w = tid >> 6, l = tid & 63;
    int wr = w >> 1, wc = w & 1;
    int m0 = blockIdx.y * GBM, n0 = blockIdx.x * GBN;

    f32x4 acc[4][4];
    #pragma unroll
    for (int m = 0; m < 4; ++m)
        #pragma unroll
        for (int n = 0; n < 4; ++n) acc[m][n] = (f32x4){0.f, 0.f, 0.f, 0.f};
    int fr = l & 15, fq = l >> 4;

    for (int k0 = 0; k0 < K; k0 += GBK) {
        GEMM_STAGE(A, B, K, K, k0)
        __syncthreads();
        GEMM_MFMA_STEP
        __syncthreads();
    }

    #pragma unroll
    for (int m = 0; m < 4; ++m)
        #pragma unroll
        for (int n = 0; n < 4; ++n) {
            int col = n0 + wc * 64 + n * 16 + fr;
            float bv = bias[col];
            #pragma unroll
            for (int j = 0; j < 4; ++j) {
                int row = m0 + wr * 64 + m * 16 + fq * 4 + j;
                float v = acc[m][n][j] + bv;
                v = fmaxf(v, 0.f) + log1pf(__expf(-fabsf(v)));   // stable softplus
                C[(size_t)row * ldc + col] = f2bf(v);
            }
        }
}

// split-K partials (GEMM4 path A): grid (N/128, M/128, KS)
__global__ __launch_bounds__(256) void gemm_bf16_nt_ks(const unsigned short* __restrict__ A, int lda,
    const unsigned short* __restrict__ B, int ldb, float* __restrict__ P,
    int M, int N, int Kper)
{
    __shared__ unsigned short As[GBM * GBK];
    __shared__ unsigned short Bs[GBN * GBK];
    int tid = threadIdx.x;
    int w = tid >> 6, l = tid & 63;
    int wr = w >> 1, wc = w & 1;
    int m0 = blockIdx.y * GBM, n0 = blockIdx.x * GBN;
    int koff = blockIdx.z * Kper;
    float* Pz = P + (size_t)blockIdx.z * M * N;

    f32x4 acc[4][4];
    #pragma unroll
    for (int m = 0; m < 4; ++m)
        #pragma unroll
        for (int n = 0; n < 4; ++n) acc[m][n] = (f32x4){0.f, 0.f, 0.f, 0.f};
    int fr = l & 15, fq = l >> 4;

    for (int k0 = 0; k0 < Kper; k0 += GBK) {
        GEMM_STAGE(A, B, lda, ldb, koff + k0)
        __syncthreads();
        GEMM_MFMA_STEP
        __syncthreads();
    }

    #pragma unroll
    for (int m = 0; m < 4; ++m)
        #pragma unroll
        for (int n = 0; n < 4; ++n) {
            int col = n0 + wc * 64 + n * 16 + fr;
            #pragma unroll
            for (int j = 0; j < 4; ++j) {
                int row = m0 + wr * 64 + m * 16 + fq * 4 + j;
                Pz[(size_t)row * N + col] = acc[m][n][j];
            }
        }
}

// sum 2 split-K partials -> (optional) f32 X and/or bf16 Xbf
__global__ __launch_bounds__(256) void gemm4_reduce(const float* __restrict__ P,
    float* __restrict__ X, unsigned short* __restrict__ Xbf)
{
    int i = blockIdx.x * 256 + threadIdx.x;
    if (i >= ROWS * D_MODEL / 4) return;
    float4 a = reinterpret_cast<const float4*>(P)[i];
    float4 b = reinterpret_cast<const float4*>(P + (size_t)ROWS * D_MODEL)[i];
    float4 r; r.x = a.x + b.x; r.y = a.y + b.y; r.z = a.z + b.z; r.w = a.w + b.w;
    if (X) reinterpret_cast<float4*>(X)[i] = r;
    if (Xbf) {
        ushort4 o; o.x = f2bf(r.x); o.y = f2bf(r.y); o.z = f2bf(r.z); o.w = f2bf(r.w);
        reinterpret_cast<ushort4*>(Xbf)[i] = o;
    }
}

// ---------------- FUSED conv+silu + GEMM2 split-K (path A) ----------------
__global__ __launch_bounds__(256) void gemm2_fused(const unsigned short* __restrict__ XZbf,
    const float* __restrict__ cw, const float* __restrict__ cb,
    const float* __restrict__ B, unsigned short* __restrict__ XCbf,
    float* __restrict__ P)
{
    __shared__ float Axc[G2_KC][68];           // 34.8 KB
    __shared__ float Bs[G2_BK][XDIM + 1];      // 12.1 KB
    int tid = threadIdx.x;
    int m0 = blockIdx.x * G2_ROWS;
    int kc = blockIdx.y;
    int k0 = kc * G2_KC;

    // ---- phase 1: conv+silu ----
    {
        int d_loc = tid & 127;
        int d     = k0 + d_loc;
        int r0    = m0 + (tid >> 7) * 32;
        float4 wv = *(const float4*)(cw + (size_t)d * 4);
        float cbv = cb[d];
        int l0 = r0 & (SEQ - 1);
        float u3 = (l0 >= 3) ? bf2f(XZbf[(size_t)(r0 - 3) * XZLD + d]) : 0.f;
        float u2 = (l0 >= 2) ? bf2f(XZbf[(size_t)(r0 - 2) * XZLD + d]) : 0.f;
        float u1 = (l0 >= 1) ? bf2f(XZbf[(size_t)(r0 - 1) * XZLD + d]) : 0.f;
        int rl0 = r0 - m0;
        #pragma unroll 4
        for (int t = 0; t < 32; ++t) {
            float u0 = bf2f(XZbf[(size_t)(r0 + t) * XZLD + d]);
            float v = cbv + wv.x * u3 + wv.y * u2 + wv.z * u1 + wv.w * u0;
            v = v / (1.f + __expf(-v));        // silu
            Axc[d_loc][rl0 + t] = v;
            XCbf[(size_t)(r0 + t) * D_INNER + d] = f2bf(v);
            u3 = u2; u2 = u1; u1 = u0;
        }
    }
    __syncthreads();

    // ---- phase 2: GEMM ----
    int rg = tid >> 4;
    int cg = tid & 15;
    float acc[4][6];
    #pragma unroll
    for (int i = 0; i < 4; ++i)
        #pragma unroll
        for (int j = 0; j < 6; ++j) acc[i][j] = 0.f;

    for (int kb = 0; kb < G2_KC; kb += G2_BK) {
        {
            #pragma unroll
            for (int i = 0; i < 3; ++i) {
                int idx = tid + i * 256;
                int col = idx >> 3;
                int kk  = (idx & 7) * 4;
                float4 v = *(const float4*)(B + (size_t)col * D_INNER + k0 + kb + kk);
                Bs[kk + 0][col] = v.x;
                Bs[kk + 1][col] = v.y;
                Bs[kk + 2][col] = v.z;
                Bs[kk + 3][col] = v.w;
            }
        }
        __syncthreads();
        #pragma unroll
        for (int k = 0; k < G2_BK; ++k) {
            float4 a  = *(const float4*)&Axc[kb + k][rg * 4];
            float2 b0 = *(const float2*)&Bs[k][cg * 6];
            float2 b1 = *(const float2*)&Bs[k][cg * 6 + 2];
            float2 b2 = *(const float2*)&Bs[k][cg * 6 + 4];
            float av[4] = {a.x, a.y, a.z, a.w};
            float bv[6] = {b0.x, b0.y, b1.x, b1.y, b2.x, b2.y};
            #pragma unroll
            for (int i = 0; i < 4; ++i)
                #pragma unroll
                for (int j = 0; j < 6; ++j) acc[i][j] += av[i] * bv[j];
        }
        __syncthreads();
    }

    #pragma unroll
    for (int i = 0; i < 4; ++i)
        #pragma unroll
        for (int j = 0; j < 6; ++j)
            P[((size_t)kc * ROWS + m0 + rg * 4 + i) * XDIM + cg * 6 + j] = acc[i][j];
}

// ---------------- GEMM2 split-K (f32, path B) ----------------
__global__ __launch_bounds__(256) void gemm2_splitk(const float* __restrict__ A,
    const float* __restrict__ B, float* __restrict__ P)
{
    __shared__ float As[G2_BK][G2_ROWS];
    __shared__ float Bs[G2_BK][XDIM + 1];
    int tid = threadIdx.x;
    int m0 = blockIdx.x * G2_ROWS;
    int kc = blockIdx.y;
    int k0 = kc * G2_KC;

    int rg = tid >> 4;
    int cg = tid & 15;
    float acc[4][6];
    #pragma unroll
    for (int i = 0; i < 4; ++i)
        #pragma unroll
        for (int j = 0; j < 6; ++j) acc[i][j] = 0.f;

    for (int kb = 0; kb < G2_KC; kb += G2_BK) {
        {
            int row = tid & 63;
            int kk  = (tid >> 6) * 4;
            #pragma unroll
            for (int i = 0; i < 2; ++i) {
                float4 v = *(const float4*)(A + (size_t)(m0 + row) * D_INNER + k0 + kb + kk + i * 16);
                As[kk + i * 16 + 0][row] = v.x;
                As[kk + i * 16 + 1][row] = v.y;
                As[kk + i * 16 + 2][row] = v.z;
                As[kk + i * 16 + 3][row] = v.w;
            }
        }
        {
            #pragma unroll
            for (int i = 0; i < 3; ++i) {
                int idx = tid + i * 256;
                int col = idx >> 3;
                int kk  = (idx & 7) * 4;
                float4 v = *(const float4*)(B + (size_t)col * D_INNER + k0 + kb + kk);
                Bs[kk + 0][col] = v.x;
                Bs[kk + 1][col] = v.y;
                Bs[kk + 2][col] = v.z;
                Bs[kk + 3][col] = v.w;
            }
        }
        __syncthreads();
        #pragma unroll
        for (int k = 0; k < G2_BK; ++k) {
            float4 a  = *(const float4*)&As[k][rg * 4];
            float2 b0 = *(const float2*)&Bs[k][cg * 6];
            float2 b1 = *(const float2*)&Bs[k][cg * 6 + 2];
            float2 b2 = *(const float2*)&Bs[k][cg * 6 + 4];
            float av[4] = {a.x, a.y, a.z, a.w};
            float bv[6] = {b0.x, b0.y, b1.x, b1.y, b2.x, b2.y};
            #pragma unroll
            for (int i = 0; i < 4; ++i)
                #pragma unroll
                for (int j = 0; j < 6; ++j) acc[i][j] += av[i] * bv[j];
        }
        __syncthreads();
    }

    #pragma unroll
    for (int i = 0; i < 4; ++i)
        #pragma unroll
        for (int j = 0; j < 6; ++j)
            P[((size_t)kc * ROWS + m0 + rg * 4 + i) * XDIM + cg * 6 + j] = acc[i][j];
}

// reduce; optionally emit dt columns as bf16
__global__ __launch_bounds__(256) void gemm2_reduce(const float* __restrict__ P,
    float* __restrict__ XDBLo, unsigned short* __restrict__ dtbf)
{
    int i = blockIdx.x * 256 + threadIdx.x;
    if (i >= ROWS * XDIM / 4) return;
    float4 acc = make_float4(0.f, 0.f, 0.f, 0.f);
    #pragma unroll
    for (int ks = 0; ks < G2_KS; ++ks) {
        float4 v = *(const float4*)(P + (size_t)ks * ROWS * XDIM + (size_t)i * 4);
        acc.x += v.x; acc.y += v.y; acc.z += v.z; acc.w += v.w;
    }
    *(float4*)(XDBLo + (size_t)i * 4) = acc;
    if (dtbf) {
        int row = (i * 4) / XDIM;
        int col = (i * 4) - row * XDIM;
        if (col < DT_RANK) {
            ushort4 o; o.x = f2bf(acc.x); o.y = f2bf(acc.y); o.z = f2bf(acc.z); o.w = f2bf(acc.w);
            *reinterpret_cast<ushort4*>(dtbf + (size_t)row * DT_RANK + col) = o;
        }
    }
}

// ---------------- generic fp32 NT GEMM (fallback path C) ----------------
#define BM 64
#define BN 64
#define BK 16
__global__ __launch_bounds__(256) void gemm_nt(const float* __restrict__ A, int lda,
                                               const float* __restrict__ B, int ldb,
                                               float* __restrict__ C, int ldc,
                                               int M, int N, int K,
                                               const float* __restrict__ bias, int epilogue)
{
    __shared__ float As[BM][BK + 1];
    __shared__ float Bs[BN][BK + 1];
    int t  = threadIdx.x;
    int m0 = blockIdx.y * BM;
    int n0 = blockIdx.x * BN;
    int lrow = t >> 2;
    int lk   = (t & 3) * 4;
    int tm   = t >> 4;
    int tn   = t & 15;

    float acc[4][4];
    #pragma unroll
    for (int i = 0; i < 4; ++i)
        #pragma unroll
        for (int j = 0; j < 4; ++j) acc[i][j] = 0.f;

    for (int k0 = 0; k0 < K; k0 += BK) {
        {
            int row = m0 + lrow;
            float4 v = make_float4(0.f, 0.f, 0.f, 0.f);
            if (row < M) v = *reinterpret_cast<const float4*>(A + (size_t)row * lda + k0 + lk);
            As[lrow][lk + 0] = v.x; As[lrow][lk + 1] = v.y;
            As[lrow][lk + 2] = v.z; As[lrow][lk + 3] = v.w;
        }
        {
            int row = n0 + lrow;
            float4 v = make_float4(0.f, 0.f, 0.f, 0.f);
            if (row < N) v = *reinterpret_cast<const float4*>(B + (size_t)row * ldb + k0 + lk);
            Bs[lrow][lk + 0] = v.x; Bs[lrow][lk + 1] = v.y;
            Bs[lrow][lk + 2] = v.z; Bs[lrow][lk + 3] = v.w;
        }
        __syncthreads();
        #pragma unroll
        for (int kk = 0; kk < BK; ++kk) {
            float a[4], b[4];
            #pragma unroll
            for (int i = 0; i < 4; ++i) a[i] = As[tm * 4 + i][kk];
            #pragma unroll
            for (int j = 0; j < 4; ++j) b[j] = Bs[tn * 4 + j][kk];
            #pragma unroll
            for (int i = 0; i < 4; ++i)
                #pragma unroll
                for (int j = 0; j < 4; ++j) acc[i][j] += a[i] * b[j];
        }
        __syncthreads();
    }

    #pragma unroll
    for (int i = 0; i < 4; ++i) {
        int m = m0 + tm * 4 + i;
        if (m >= M) continue;
        #pragma unroll
        for (int j = 0; j < 4; ++j) {
            int n = n0 + tn * 4 + j;
            if (n >= N) continue;
            float v = acc[i][j];
            if (epilogue == 1) {
                v += bias[n];
                v = fmaxf(v, 0.f) + log1pf(__expf(-fabsf(v)));
            }
            C[(size_t)m * ldc + n] = v;
        }
    }
}

// ---------------- conv+silu, f32 (paths B/C) ----------------
__global__ __launch_bounds__(256) void conv_silu_kernel(const float* __restrict__ XZ,
    const float* __restrict__ cw, const float* __restrict__ cb, float* __restrict__ XC)
{
    int idx = blockIdx.x * 256 + threadIdx.x;
    if (idx >= ROWS * (D_INNER / 4)) return;
    int d4   = idx % (D_INNER / 4);
    int rl   = idx / (D_INNER / 4);
    int l    = rl & (SEQ - 1);
    int base = rl - l;
    int d    = d4 * 4;

    float4 acc = reinterpret_cast<const float4*>(cb)[d4];
    float w[4][4];
    #pragma unroll
    for (int dd = 0; dd < 4; ++dd) {
        float4 wv = *reinterpret_cast<const float4*>(cw + (size_t)(d + dd) * 4);
        w[dd][0] = wv.x; w[dd][1] = wv.y; w[dd][2] = wv.z; w[dd][3] = wv.w;
    }
    #pragma unroll
    for (int k = 0; k < 4; ++k) {
        int lr = l - 3 + k;
        if (lr < 0) continue;
        float4 u = *reinterpret_cast<const float4*>(XZ + (size_t)(base + lr) * XZLD + d);
        acc.x += w[0][k] * u.x; acc.y += w[1][k] * u.y;
        acc.z += w[2][k] * u.z; acc.w += w[3][k] * u.w;
    }
    acc.x = acc.x / (1.f + __expf(-acc.x));
    acc.y = acc.y / (1.f + __expf(-acc.y));
    acc.z = acc.z / (1.f + __expf(-acc.z));
    acc.w = acc.w / (1.f + __expf(-acc.w));
    reinterpret_cast<float4*>(XC)[idx] = acc;
}

// ================= chunked scan, thread-per-channel (CL=32/NC=32) =================
// Fast path: when a[s] == -(s+1) (runtime-verified), exp(dl*a[s]) = exp(-dl)^(s+1).

// path A phase 1: delta bf16 dense (DL), u bf16 dense (XCbf)
__global__ __launch_bounds__(SDB) void scan_part1b(const unsigned short* __restrict__ XCbf,
    const unsigned short* __restrict__ DL, const float* __restrict__ XDBL,
    const float* __restrict__ A_log, float* __restrict__ Psum, float* __restrict__ Ssum)
{
    __shared__ float sB[CL][16];
    int tid = threadIdx.x;
    int d = blockIdx.x * SDB + tid;
    int c = blockIdx.y, b = blockIdx.z;
    size_t r0 = (size_t)b * SEQ + (size_t)c * CL;

    if (tid < CL * 4) {
        int t = tid >> 2, j = (tid & 3) * 4;
        *(float4*)&sB[t][j] = *(const float4*)(XDBL + (r0 + t) * XDIM + DT_RANK + j);
    }

    float a[D_STATE], S[D_STATE];
    #pragma unroll
    for (int i = 0; i < 4; ++i) {
        float4 v = *(const float4*)(A_log + (size_t)d * D_STATE + i * 4);
        a[i*4+0] = -__expf(v.x); a[i*4+1] = -__expf(v.y);
        a[i*4+2] = -__expf(v.z); a[i*4+3] = -__expf(v.w);
    }
    bool powok = true;
    #pragma unroll
    for (int s = 0; s < D_STATE; ++s)
        powok = powok && (fabsf(a[s] + (float)(s + 1)) < 1e-3f * (float)(s + 1));
    #pragma unroll
    for (int s = 0; s < D_STATE; ++s) S[s] = 0.f;
    float sumdl = 0.f;
    __syncthreads();

    if (powok) {
        for (int t = 0; t < CL; ++t) {
            float dl = bf2f(DL[(r0 + t) * D_INNER + d]);
            float uu = bf2f(XCbf[(r0 + t) * D_INNER + d]);
            float du = dl * uu;
            sumdl += dl;
            float4 b0 = *(const float4*)&sB[t][0];
            float4 b1 = *(const float4*)&sB[t][4];
            float4 b2 = *(const float4*)&sB[t][8];
            float4 b3 = *(const float4*)&sB[t][12];
            float bv[16] = {b0.x,b0.y,b0.z,b0.w, b1.x,b1.y,b1.z,b1.w,
                            b2.x,b2.y,b2.z,b2.w, b3.x,b3.y,b3.z,b3.w};
            float e1 = __expf(-dl);
            float E[16];
            POW_TREE(E, e1)
            #pragma unroll
            for (int s = 0; s < D_STATE; ++s)
                S[s] = E[s] * S[s] + du * bv[s];
        }
    } else {
        for (int t = 0; t < CL; ++t) {
            float dl = bf2f(DL[(r0 + t) * D_INNER + d]);
            float uu = bf2f(XCbf[(r0 + t) * D_INNER + d]);
            float du = dl * uu;
            sumdl += dl;
            float4 b0 = *(const float4*)&sB[t][0];
            float4 b1 = *(const float4*)&sB[t][4];
            float4 b2 = *(const float4*)&sB[t][8];
            float4 b3 = *(const float4*)&sB[t][12];
            float bv[16] = {b0.x,b0.y,b0.z,b0.w, b1.x,b1.y,b1.z,b1.w,
                            b2.x,b2.y,b2.z,b2.w, b3.x,b3.y,b3.z,b3.w};
            #pragma unroll
            for (int s = 0; s < D_STATE; ++s) {
                float e = __expf(dl * a[s]);
                S[s] = e * S[s] + du * bv[s];
            }
        }
    }

    size_t o = (((size_t)b * NC + c) * D_INNER + d) * D_STATE;
    #pragma unroll
    for (int i = 0; i < 4; ++i) {
        float4 p, s4;
        p.x = __expf(a[i*4+0] * sumdl); p.y = __expf(a[i*4+1] * sumdl);
        p.z = __expf(a[i*4+2] * sumdl); p.w = __expf(a[i*4+3] * sumdl);
        s4.x = S[i*4+0]; s4.y = S[i*4+1]; s4.z = S[i*4+2]; s4.w = S[i*4+3];
        *(float4*)(Psum + o + i * 4) = p;
        *(float4*)(Ssum + o + i * 4) = s4;
    }
}

// chunk-level prefix, in place
__global__ __launch_bounds__(256) void scan_prefix(float* __restrict__ Psum,
    const float* __restrict__ Ssum)
{
    int idx = blockIdx.x * 256 + threadIdx.x;
    int b = idx >> 15;
    int rem = idx & 32767;
    float h = 0.f;
    for (int c = 0; c < NC; ++c) {
        size_t o = (((size_t)b * NC + c) * D_INNER * D_STATE) + rem;
        float p = Psum[o];
        float s = Ssum[o];
        Psum[o] = h;
        h = p * h + s;
    }
}

// path A phase 2: out bf16 in place (DL) -> GEMM4 A
__global__ __launch_bounds__(SDB) void scan_part2b(const unsigned short* __restrict__ XCbf,
    unsigned short* __restrict__ DL, const unsigned short* __restrict__ XZbf,
    const float* __restrict__ XDBL, const float* __restrict__ A_log,
    const float* __restrict__ Dp, const float* __restrict__ Hin)
{
    __shared__ float sBC[CL][32];
    int tid = threadIdx.x;
    int d = blockIdx.x * SDB + tid;
    int c = blockIdx.y, b = blockIdx.z;
    size_t r0 = (size_t)b * SEQ + (size_t)c * CL;

    {
        int t = tid >> 3, j = (tid & 7) * 4;
        *(float4*)&sBC[t][j] = *(const float4*)(XDBL + (r0 + t) * XDIM + DT_RANK + j);
    }

    float a[D_STATE], h[D_STATE];
    #pragma unroll
    for (int i = 0; i < 4; ++i) {
        float4 v = *(const float4*)(A_log + (size_t)d * D_STATE + i * 4);
        a[i*4+0] = -__expf(v.x); a[i*4+1] = -__expf(v.y);
        a[i*4+2] = -__expf(v.z); a[i*4+3] = -__expf(v.w);
    }
    bool powok = true;
    #pragma unroll
    for (int s = 0; s < D_STATE; ++s)
        powok = powok && (fabsf(a[s] + (float)(s + 1)) < 1e-3f * (float)(s + 1));
    size_t ho = (((size_t)b * NC + c) * D_INNER + d) * D_STATE;
    #pragma unroll
    for (int i = 0; i < 4; ++i) {
        float4 v = *(const float4*)(Hin + ho + i * 4);
        h[i*4+0] = v.x; h[i*4+1] = v.y; h[i*4+2] = v.z; h[i*4+3] = v.w;
    }
    float dp = Dp[d];
    __syncthreads();

    if (powok) {
        for (int t = 0; t < CL; ++t) {
            float dl = bf2f(DL[(r0 + t) * D_INNER + d]);
            float uu = bf2f(XCbf[(r0 + t) * D_INNER + d]);
            float z  = bf2f(XZbf[(r0 + t) * XZLD + D_INNER + d]);
            float du = dl * uu;
            float4 b0 = *(const float4*)&sBC[t][0];
            float4 b1 = *(const float4*)&sBC[t][4];
            float4 b2 = *(const float4*)&sBC[t][8];
            float4 b3 = *(const float4*)&sBC[t][12];
            float4 c0 = *(const float4*)&sBC[t][16];
            float4 c1 = *(const float4*)&sBC[t][20];
            float4 c2 = *(const float4*)&sBC[t][24];
            float4 c3 = *(const float4*)&sBC[t][28];
            float bv[16] = {b0.x,b0.y,b0.z,b0.w, b1.x,b1.y,b1.z,b1.w,
                            b2.x,b2.y,b2.z,b2.w, b3.x,b3.y,b3.z,b3.w};
            float cv[16] = {c0.x,c0.y,c0.z,c0.w, c1.x,c1.y,c1.z,c1.w,
                            c2.x,c2.y,c2.z,c2.w, c3.x,c3.y,c3.z,c3.w};
            float e1 = __expf(-dl);
            float E[16];
            POW_TREE(E, e1)
            float y = 0.f;
            #pragma unroll
            for (int s = 0; s < D_STATE; ++s) {
                h[s] = E[s] * h[s] + du * bv[s];
                y += h[s] * cv[s];
            }
            float sz = z / (1.f + __expf(-z));
            DL[(r0 + t) * D_INNER + d] = f2bf((y + uu * dp) * sz);
        }
    } else {
        for (int t = 0; t < CL; ++t) {
            float dl = bf2f(DL[(r0 + t) * D_INNER + d]);
            float uu = bf2f(XCbf[(r0 + t) * D_INNER + d]);
            float z  = bf2f(XZbf[(r0 + t) * XZLD + D_INNER + d]);
            float du = dl * uu;
            float4 b0 = *(const float4*)&sBC[t][0];
            float4 b1 = *(const float4*)&sBC[t][4];
            float4 b2 = *(const float4*)&sBC[t][8];
            float4 b3 = *(const float4*)&sBC[t][12];
            float4 c0 = *(const float4*)&sBC[t][16];
            float4 c1 = *(const float4*)&sBC[t][20];
            float4 c2 = *(const float4*)&sBC[t][24];
            float4 c3 = *(const float4*)&sBC[t][28];
            float bv[16] = {b0.x,b0.y,b0.z,b0.w, b1.x,b1.y,b1.z,b1.w,
                            b2.x,b2.y,b2.z,b2.w, b3.x,b3.y,b3.z,b3.w};
            float cv[16] = {c0.x,c0.y,c0.z,c0.w, c1.x,c1.y,c1.z,c1.w,
                            c2.x,c2.y,c2.z,c2.w, c3.x,c3.y,c3.z,c3.w};
            float y = 0.f;
            #pragma unroll
            for (int s = 0; s < D_STATE; ++s) {
                float e = __expf(dl * a[s]);
                h[s] = e * h[s] + du * bv[s];
                y += h[s] * cv[s];
            }
            float sz = z / (1.f + __expf(-z));
            DL[(r0 + t) * D_INNER + d] = f2bf((y + uu * dp) * sz);
        }
    }
}

// ---- path B scan variants (f32) ----
__global__ __launch_bounds__(SDB) void scan_part1(const float* __restrict__ XC,
    const float* __restrict__ XZ, const float* __restrict__ XDBL,
    const float* __restrict__ A_log, float* __restrict__ Psum, float* __restrict__ Ssum)
{
    __shared__ float sB[CL][16];
    int tid = threadIdx.x;
    int d = blockIdx.x * SDB + tid;
    int c = blockIdx.y, b = blockIdx.z;
    size_t r0 = (size_t)b * SEQ + (size_t)c * CL;

    if (tid < CL * 4) {
        int t = tid >> 2, j = (tid & 3) * 4;
        *(float4*)&sB[t][j] = *(const float4*)(XDBL + (r0 + t) * XDIM + DT_RANK + j);
    }

    float a[D_STATE], S[D_STATE];
    #pragma unroll
    for (int i = 0; i < 4; ++i) {
        float4 v = *(const float4*)(A_log + (size_t)d * D_STATE + i * 4);
        a[i*4+0] = -__expf(v.x); a[i*4+1] = -__expf(v.y);
        a[i*4+2] = -__expf(v.z); a[i*4+3] = -__expf(v.w);
    }
    #pragma unroll
    for (int s = 0; s < D_STATE; ++s) S[s] = 0.f;
    float sumdl = 0.f;
    __syncthreads();

    for (int t = 0; t < CL; ++t) {
        float dl = XZ[(r0 + t) * XZLD + d];
        float uu = XC[(r0 + t) * D_INNER + d];
        float du = dl * uu;
        sumdl += dl;
        float4 b0 = *(const float4*)&sB[t][0];
        float4 b1 = *(const float4*)&sB[t][4];
        float4 b2 = *(const float4*)&sB[t][8];
        float4 b3 = *(const float4*)&sB[t][12];
        float bv[16] = {b0.x,b0.y,b0.z,b0.w, b1.x,b1.y,b1.z,b1.w,
                        b2.x,b2.y,b2.z,b2.w, b3.x,b3.y,b3.z,b3.w};
        #pragma unroll
        for (int s = 0; s < D_STATE; ++s) {
            float e = __expf(dl * a[s]);
            S[s] = e * S[s] + du * bv[s];
        }
    }

    size_t o = (((size_t)b * NC + c) * D_INNER + d) * D_STATE;
    #pragma unroll
    for (int i = 0; i < 4; ++i) {
        float4 p, s4;
        p.x = __expf(a[i*4+0] * sumdl); p.y = __expf(a[i*4+1] * sumdl);
        p.z = __expf(a[i*4+2] * sumdl); p.w = __expf(a[i*4+3] * sumdl);
        s4.x = S[i*4+0]; s4.y = S[i*4+1]; s4.z = S[i*4+2]; s4.w = S[i*4+3];
        *(float4*)(Psum + o + i * 4) = p;
        *(float4*)(Ssum + o + i * 4) = s4;
    }
}

__global__ __launch_bounds__(SDB) void scan_part2(const float* __restrict__ XC,
    float* __restrict__ XZ, const float* __restrict__ XDBL,
    const float* __restrict__ A_log, const float* __restrict__ Dp,
    const float* __restrict__ Hin)
{
    __shared__ float sBC[CL][32];
    int tid = threadIdx.x;
    int d = blockIdx.x * SDB + tid;
    int c = blockIdx.y, b = blockIdx.z;
    size_t r0 = (size_t)b * SEQ + (size_t)c * CL;

    {
        int t = tid >> 3, j = (tid & 7) * 4;
        *(float4*)&sBC[t][j] = *(const float4*)(XDBL + (r0 + t) * XDIM + DT_RANK + j);
    }

    float a[D_STATE], h[D_STATE];
    #pragma unroll
    for (int i = 0; i < 4; ++i) {
        float4 v = *(const float4*)(A_log + (size_t)d * D_STATE + i * 4);
        a[i*4+0] = -__expf(v.x); a[i*4+1] = -__expf(v.y);
        a[i*4+2] = -__expf(v.z); a[i*4+3] = -__expf(v.w);
    }
    size_t ho = (((size_t)b * NC + c) * D_INNER + d) * D_STATE;
    #pragma unroll
    for (int i = 0; i < 4; ++i) {
        float4 v = *(const float4*)(Hin + ho + i * 4);
        h[i*4+0] = v.x; h[i*4+1] = v.y; h[i*4+2] = v.z; h[i*4+3] = v.w;
    }
    float dp = Dp[d];
    __syncthreads();

    for (int t = 0; t < CL; ++t) {
        float dl = XZ[(r0 + t) * XZLD + d];
        float uu = XC[(r0 + t) * D_INNER + d];
        float z  = XZ[(r0 + t) * XZLD + D_INNER + d];
        float du = dl * uu;
        float4 b0 = *(const float4*)&sBC[t][0];
        float4 b1 = *(const float4*)&sBC[t][4];
        float4 b2 = *(const float4*)&sBC[t][8];
        float4 b3 = *(const float4*)&sBC[t][12];
        float4 c0 = *(const float4*)&sBC[t][16];
        float4 c1 = *(const float4*)&sBC[t][20];
        float4 c2 = *(const float4*)&sBC[t][24];
        float4 c3 = *(const float4*)&sBC[t][28];
        float bv[16] = {b0.x,b0.y,b0.z,b0.w, b1.x,b1.y,b1.z,b1.w,
                        b2.x,b2.y,b2.z,b2.w, b3.x,b3.y,b3.z,b3.w};
        float cv[16] = {c0.x,c0.y,c0.z,c0.w, c1.x,c1.y,c1.z,c1.w,
                        c2.x,c2.y,c2.z,c2.w, c3.x,c3.y,c3.z,c3.w};
        float y = 0.f;
        #pragma unroll
        for (int s = 0; s < D_STATE; ++s) {
            float e = __expf(dl * a[s]);
            h[s] = e * h[s] + du * bv[s];
            y += h[s] * cv[s];
        }
        float sz = z / (1.f + __expf(-z));
        XZ[(r0 + t) * XZLD + d] = (y + uu * dp) * sz;
    }
}

// ---------------- fallback sequential scan (path C) ----------------
__global__ __launch_bounds__(256) void scan_kernel2(const float* __restrict__ XC,
    float* __restrict__ XZ, const float* __restrict__ XDBL,
    const float* __restrict__ A_log, const float* __restrict__ Dp)
{
    int tid = threadIdx.x;
    int s  = tid & 15;
    int dd = tid >> 4;
    int d  = blockIdx.x * 16 + dd;
    int b  = blockIdx.y;

    float a  = -__expf(A_log[(size_t)d * D_STATE + s]);
    float h  = 0.f;
    float dp = Dp[d];
    const size_t rbase = (size_t)b * SEQ;

    for (int t = 0; t < SEQ; ++t) {
        size_t r = rbase + t;
        float dl = XZ[r * XZLD + d];
        float uu = XC[r * D_INNER + d];
        float z  = XZ[r * XZLD + D_INNER + d];
        float Bv = XDBL[r * XDIM + DT_RANK + s];
        float Cv = XDBL[r * XDIM + DT_RANK + D_STATE + s];
        float e  = __expf(dl * a);
        h = e * h + dl * uu * Bv;
        float y = h * Cv;
        y += __shfl_xor(y, 1);
        y += __shfl_xor(y, 2);
        y += __shfl_xor(y, 4);
        y += __shfl_xor(y, 8);
        if (s == 0) {
            float sz = z / (1.f + __expf(-z));
            XZ[r * XZLD + d] = (y + uu * dp) * sz;
        }
    }
}

extern "C" void kernel_launch(void* const* d_in, const int* in_sizes, int n_in,
                              void* d_out, int out_size, void* d_ws, size_t ws_size,
                              hipStream_t stream)
{
    const float* pe    = (const float*)d_in[0];
    const float* cond  = (const float*)d_in[1];
    const float* W_in  = (const float*)d_in[2];
    const float* cw    = (const float*)d_in[3];
    const float* cb    = (const float*)d_in[4];
    const float* W_x   = (const float*)d_in[5];
    const float* W_dt  = (const float*)d_in[6];
    const float* b_dt  = (const float*)d_in[7];
    const float* A_log = (const float*)d_in[8];
    const float* Dp    = (const float*)d_in[9];
    const float* W_out = (const float*)d_in[10];

    float* X = (float*)d_out;                          // [2048,1024] final output only

    // ---------------- path A layout (~86 MB) ----------------
    char* wsp = (char*)d_ws;
    unsigned short* XZbf = (unsigned short*)wsp;                       // [2048][4096] 16.8MB
    unsigned short* XCbf = (unsigned short*)(wsp + 16777216);          // [2048][2048] bf16 8.4MB
    float* XDBL  = (float*)(wsp + 33554432);                           // [2048][96]   0.8MB
    unsigned short* BF0   = (unsigned short*)(wsp + 34340864);         // [2048][2048] 8.4MB (x/delta/out)
    unsigned short* dtbf  = (unsigned short*)(wsp + 42729472);         // [2048][64]   0.26MB
    unsigned short* WINbf = (unsigned short*)(wsp + 42991616);         // 2x[4096][1024] 16.8MB
    unsigned short* WOUTbf= (unsigned short*)(wsp + 59768832);         // 2x[1024][2048] 8.4MB
    unsigned short* WDTbf = (unsigned short*)(wsp + 68157440);         // 2x[2048][64]  0.52MB
    float* SCR   = (float*)(wsp + 68681728);                           // 16.8MB scratch
    size_t need_A = 68681728 + 16777216;                               // ~85.5MB

    // ---------------- path B layout (round-6, ~68MB) ----------------
    float* XZb   = (float*)d_ws;
    float* XCb   = XZb + (size_t)ROWS * XZLD;
    float* XDBLb = XCb + (size_t)ROWS * D_INNER;
    void* rest = (void*)(XDBLb + (size_t)ROWS * XDIM);
    unsigned short* Abf = (unsigned short*)rest;
    unsigned short* Bbf = Abf + (size_t)ROWS * D_INNER;
    float* PpartB = (float*)rest;
    float* PsumB  = (float*)rest;
    float* SsumB  = PsumB + (size_t)BATCH * NC * D_INNER * D_STATE;
    size_t need_B = ((size_t)ROWS * XZLD + (size_t)ROWS * D_INNER + (size_t)ROWS * XDIM) * 4
                  + ((size_t)ROWS * D_INNER + (size_t)ROWS * D_INNER) * 2;

    if (ws_size >= need_A) {
        // =========================== PATH A ===========================
        float* Psum = SCR;                                             // 8.4MB (NC=32)
        float* Ssum = SCR + (size_t)BATCH * NC * D_INNER * D_STATE;    // 8.4MB

        // one-time: all weights + x -> bf16 in ONE dispatch
        conv_wall<<<(WN1 + WN2 + WN3 + WN4 + 255) / 256, 256, 0, stream>>>(
            W_in, W_out, W_dt, pe, cond, WINbf, WOUTbf, WDTbf, BF0);

        for (int l = 0; l < NLAYERS; ++l) {
            const unsigned short* WINl  = WINbf  + (size_t)l * 2 * D_INNER * D_MODEL;
            const unsigned short* WOUTl = WOUTbf + (size_t)l * D_MODEL * D_INNER;
            const unsigned short* WDTl  = WDTbf  + (size_t)l * D_INNER * DT_RANK;
            const float* W_x_l   = W_x   + (size_t)l * XDIM * D_INNER;
            const float* cw_l    = cw    + (size_t)l * D_INNER * 4;
            const float* cb_l    = cb    + (size_t)l * D_INNER;
            const float* b_dt_l  = b_dt  + (size_t)l * D_INNER;
            const float* A_log_l = A_log + (size_t)l * D_INNER * D_STATE;
            const float* Dp_l    = Dp    + (size_t)l * D_INNER;

            // GEMM1: xz(bf16) = x(bf16) @ W_in^T   (BF0 holds x: conv_wall for l0, gemm4_reduce for l1)
            gemm_bf16_nt_bfout<<<dim3(2 * D_INNER / GBN, ROWS / GBM), 256, 0, stream>>>(
                BF0, WINl, XZbf, ROWS, 2 * D_INNER, D_MODEL, XZLD);
            // FUSED conv+silu + GEMM2 split-K (xc -> XCbf bf16, partials -> SCR)
            gemm2_fused<<<dim3(ROWS / G2_ROWS, G2_KS), 256, 0, stream>>>(
                XZbf, cw_l, cb_l, W_x_l, XCbf, SCR);
            gemm2_reduce<<<(ROWS * XDIM / 4 + 255) / 256, 256, 0, stream>>>(SCR, XDBL, dtbf);
            // GEMM3: delta(bf16 dense) = softplus(dt @ W_dt^T + b_dt) -> BF0
            gemm_bf16_sp_bfout<<<dim3(D_INNER / GBN, ROWS / GBM), 256, 0, stream>>>(
                dtbf, WDTl, BF0, ROWS, D_INNER, DT_RANK, D_INNER, b_dt_l);
            // chunked scan (out bf16 in place -> GEMM4 A)
            scan_part1b<<<dim3(D_INNER / SDB, NC, BATCH), SDB, 0, stream>>>(
                XCbf, BF0, XDBL, A_log_l, Psum, Ssum);
            scan_prefix<<<BATCH * D_INNER * D_STATE / 256, 256, 0, stream>>>(Psum, Ssum);
            scan_part2b<<<dim3(D_INNER / SDB, NC, BATCH), SDB, 0, stream>>>(
                XCbf, BF0, XZbf, XDBL, A_log_l, Dp_l, Psum);
            // GEMM4 split-K=2 -> SCR, reduce -> (l0: BF0 bf16) / (l1: X f32)
            gemm_bf16_nt_ks<<<dim3(D_MODEL / GBN, ROWS / GBM, 2), 256, 0, stream>>>(
                BF0, D_INNER, WOUTl, D_INNER, SCR, ROWS, D_MODEL, D_INNER / 2);
            gemm4_reduce<<<(ROWS * D_MODEL / 4 + 255) / 256, 256, 0, stream>>>(
                SCR, (l == NLAYERS - 1) ? X : nullptr, (l < NLAYERS - 1) ? BF0 : nullptr);
        }
    } else if (ws_size >= need_B) {
        // =========================== PATH B (round-6) ===========================
        add_pe_kernel<<<ROWS * D_MODEL / 4 / 256, 256, 0, stream>>>(pe, cond, X);
        for (int l = 0; l < NLAYERS; ++l) {
            const float* W_in_l  = W_in  + (size_t)l * 2 * D_INNER * D_MODEL;
            const float* W_out_l = W_out + (size_t)l * D_MODEL * D_INNER;
            const float* W_x_l   = W_x   + (size_t)l * XDIM * D_INNER;
            const float* W_dt_l  = W_dt  + (size_t)l * D_INNER * DT_RANK;
            const float* b_dt_l  = b_dt  + (size_t)l * D_INNER;
            const float* A_log_l = A_log + (size_t)l * D_INNER * D_STATE;
            const float* Dp_l    = Dp    + (size_t)l * D_INNER;

            conv_bf16_dense<<<(ROWS * D_MODEL / 4 + 255) / 256, 256, 0, stream>>>(X, Abf, ROWS * D_MODEL / 4);
            conv_bf16_dense<<<(2 * D_INNER * D_MODEL / 4 + 255) / 256, 256, 0, stream>>>(W_in_l, Bbf, 2 * D_INNER * D_MODEL / 4);
            gemm_bf16_nt<<<dim3(2 * D_INNER / GBN, ROWS / GBM), 256, 0, stream>>>(
                Abf, Bbf, XZb, ROWS, 2 * D_INNER, D_MODEL, XZLD, nullptr, 0);
            conv_silu_kernel<<<ROWS * (D_INNER / 4) / 256, 256, 0, stream>>>(
                XZb, cw + (size_t)l * D_INNER * 4, cb + (size_t)l * D_INNER, XCb);
            gemm2_splitk<<<dim3(ROWS / G2_ROWS, G2_KS), 256, 0, stream>>>(XCb, W_x_l, PpartB);
            gemm2_reduce<<<(ROWS * XDIM / 4 + 255) / 256, 256, 0, stream>>>(PpartB, XDBLb, nullptr);
            conv_bf16_dtcols<<<(ROWS * DT_RANK / 4 + 255) / 256, 256, 0, stream>>>(XDBLb, Abf);
            conv_bf16_dense<<<(D_INNER * DT_RANK / 4 + 255) / 256, 256, 0, stream>>>(W_dt_l, Bbf, D_INNER * DT_RANK / 4);
            gemm_bf16_nt<<<dim3(D_INNER / GBN, ROWS / GBM), 256, 0, stream>>>(
                Abf, Bbf, XZb, ROWS, D_INNER, DT_RANK, XZLD, b_dt_l, 1);
            scan_part1<<<dim3(D_INNER / SDB, NC, BATCH), SDB, 0, stream>>>(
                XCb, XZb, XDBLb, A_log_l, PsumB, SsumB);
            scan_prefix<<<BATCH * D_INNER * D_STATE / 256, 256, 0, stream>>>(PsumB, SsumB);
            scan_part2<<<dim3(D_INNER / SDB, NC, BATCH), SDB, 0, stream>>>(
                XCb, XZb, XDBLb, A_log_l, Dp_l, PsumB);
            conv_bf16_strided<<<(ROWS * D_INNER / 4 + 255) / 256, 256, 0, stream>>>(
                XZb, XZLD, D_INNER, Abf, ROWS * D_INNER / 4);
            conv_bf16_dense<<<(D_MODEL * D_INNER / 4 + 255) / 256, 256, 0, stream>>>(W_out_l, Bbf, D_MODEL * D_INNER / 4);
            gemm_bf16_nt<<<dim3(D_MODEL / GBN, ROWS / GBM), 256, 0, stream>>>(
                Abf, Bbf, X, ROWS, D_MODEL, D_INNER, D_MODEL, nullptr, 0);
        }
    } else {
        // =========================== PATH C (fp32) ===========================
        add_pe_kernel<<<ROWS * D_MODEL / 4 / 256, 256, 0, stream>>>(pe, cond, X);
        for (int l = 0; l < NLAYERS; ++l) {
            gemm_nt<<<dim3(2 * D_INNER / BN, ROWS / BM), 256, 0, stream>>>(
                X, D_MODEL, W_in + (size_t)l * 2 * D_INNER * D_MODEL, D_MODEL,
                XZb, XZLD, ROWS, 2 * D_INNER, D_MODEL, nullptr, 0);
            conv_silu_kernel<<<ROWS * (D_INNER / 4) / 256, 256, 0, stream>>>(
                XZb, cw + (size_t)l * D_INNER * 4, cb + (size_t)l * D_INNER, XCb);
            gemm_nt<<<dim3((XDIM + BN - 1) / BN, ROWS / BM), 256, 0, stream>>>(
                XCb, D_INNER, W_x + (size_t)l * XDIM * D_INNER, D_INNER,
                XDBLb, XDIM, ROWS, XDIM, D_INNER, nullptr, 0);
            gemm_nt<<<dim3(D_INNER / BN, ROWS / BM), 256, 0, stream>>>(
                XDBLb, XDIM, W_dt + (size_t)l * D_INNER * DT_RANK, DT_RANK,
                XZb, XZLD, ROWS, D_INNER, DT_RANK, b_dt + (size_t)l * D_INNER, 1);
            scan_kernel2<<<dim3(D_INNER / 16, BATCH), 256, 0, stream>>>(
                XCb, XZb, XDBLb, A_log + (size_t)l * D_INNER * D_STATE, Dp + (size_t)l * D_INNER);
            gemm_nt<<<dim3(D_MODEL / BN, ROWS / BM), 256, 0, stream>>>(
                XZb, XZLD, W_out + (size_t)l * D_MODEL * D_INNER, D_INNER,
                X, D_MODEL, ROWS, D_MODEL, D_INNER, nullptr, 0);
        }
    }
}